// Round 3
// baseline (892.593 us; speedup 1.0000x reference)
//
#include <hip/hip_runtime.h>
#include <hip/hip_bf16.h>

// SparseConvNet on MI355X — Round 13: LDS diet -> 3 blocks/CU + setprio.
// R12: conv16m<7,11> 211.8us, MfmaUtil 21.6%, VALUBusy 37.6%, occupancy
// 20.7% (2 blocks/CU: LDS 56832 > 163840/3). Bank-conflict 2.778e7 is
// byte-identical across the sinv rewrite -> structural b128 multi-phase
// cost, not avoidable aliasing; dropped as a target. A-read LDS pipe
// ~128us + MFMA 45us + VALU 80us vs dur 211 -> overlap-limited. Fix:
// mprev stored as bf16 (5776->2888 B) -> 53.8KB -> 3 blocks/CU (3 w/SIMD,
// VGPR 88 <= 128 keeps 4-wave cap); s_setprio(1) around MFMA clusters
// (phase-diverse waves at 3 blocks/CU). Predict conv16m<7,11> ~170us,
// occupancy ~31%, total ~780us. NHWC plumbing frozen.

#define HW (1024 * 1024)
typedef __hip_bfloat16 bf16;
typedef __attribute__((ext_vector_type(8))) short s8v;     // 8 bf16 = 4 VGPR
typedef __attribute__((ext_vector_type(4))) float f4v;     // MFMA acc

__device__ __forceinline__ float b2f(bf16 v) { return __bfloat162float(v); }
__device__ __forceinline__ bf16  f2b(float v) { return __float2bfloat16(v); }
__device__ __forceinline__ short fbits(float v) {
    bf16 t = f2b(v); short s; __builtin_memcpy(&s, &t, 2); return s;
}
__device__ __forceinline__ float bs2f(short s) {
    bf16 t; __builtin_memcpy(&t, &s, 2); return __bfloat162float(t);
}

__device__ __forceinline__ float ldv(const void* p, int i, bool isf) {
    return isf ? ((const float*)p)[i] : b2f(((const bf16*)p)[i]);
}

__device__ __forceinline__ float wave_reduce(float v) {
    #pragma unroll
    for (int off = 32; off > 0; off >>= 1)
        v += __shfl_down(v, off, 64);
    return v;
}

// ---------------- dtype probe: 1.0 = fp32 dataset, 0.0 = bf16 ----------------
__global__ void probeKernel(const unsigned short* __restrict__ xb,
                            float* __restrict__ stats)
{
    __shared__ int sbad;
    const int tid = threadIdx.x;
    if (tid == 0) sbad = 0;
    __syncthreads();
    int bad = 0;
    for (int i = tid; i < 4096; i += 256) {
        unsigned u = ((unsigned)xb[i]) << 16;
        float v = __uint_as_float(u);
        if (!(v >= 0.f && v < 1.f)) bad = 1;
    }
    if (bad) sbad = 1;
    __syncthreads();
    if (tid == 0) stats[380] = sbad ? 1.f : 0.f;
}

// ---- L1 weights for MFMA B: wb[((k8*16+co)*8)+j] = w[co][tap(k8*8+j)], bf16 -
// tap axis: k = dy*16 + dx, K = 192; dy in 0..11, dx in 0..15; pad -> 0.
__global__ void transposeW1(const void* __restrict__ w, bf16* __restrict__ wb,
                            const float* flagp)
{
    const bool isf = (*flagp > 0.5f);
    int j = blockIdx.x * 256 + threadIdx.x;
    if (j < 3072) {
        int col8 = j & 7;
        int co = (j >> 3) & 15;
        int k8 = j >> 7;
        int k = k8 * 8 + col8;
        int dy = k >> 4, dx = k & 15;
        float v = (dy < 11 && dx < 11) ? ldv(w, co * 121 + dy * 11 + dx, isf) : 0.f;
        wb[j] = f2b(v);
    }
}

// ---- L2-5 weights for MFMA B: wtB[((t*16+co)*16)+c] = w[co][c][t], bf16 -----
__global__ void transposeWB(const void* __restrict__ w, bf16* __restrict__ wtB,
                            int KK, int NT, const float* flagp)
{
    const bool isf = (*flagp > 0.5f);
    int j = blockIdx.x * 256 + threadIdx.x;
    if (j < NT * 256) {
        int t = j >> 8, co = (j >> 4) & 15, c = j & 15;
        float v = (t < KK) ? ldv(w, (co * 16 + c) * KK + t, isf) : 0.f;
        wtB[j] = f2b(v);
    }
}

// ---------------- composed mask tile (separable max over WP window) ----------
// OT = float (fp32 store) or short (bf16 store, for LDS-dieted conv16m).
template <int TM, int TK, int WP, typename OT>
__device__ __forceinline__ void buildMaskTile(
    const void* __restrict__ mask0, bool isf, float* sm0, float* vm,
    OT* mprev, int bx, int by, int tid)
{
    constexpr int H1 = (TM - 32) / 2;
    constexpr int H2 = (TK - 32) / 2;
    for (int i = tid; i < TM * TM; i += 256) {
        int yy = by - H1 + i / TM, xx = bx - H1 + i % TM;
        float m = 0.f;
        if ((unsigned)yy < 1024u && (unsigned)xx < 1024u)
            m = ldv(mask0, (yy << 10) + xx, isf);
        sm0[i] = m;
    }
    __syncthreads();
    for (int i = tid; i < TK * TM; i += 256) {
        int y = i / TM, xc = i % TM;
        float mx = 0.f;
        for (int d = 0; d < WP; ++d) mx = fmaxf(mx, sm0[(y + d) * TM + xc]);
        vm[i] = mx;
    }
    __syncthreads();
    for (int i = tid; i < TK * TK; i += 256) {
        int y = i / TK, xc = i % TK;
        int gy = by - H2 + y, gx = bx - H2 + xc;
        float mx = 0.f;
        if ((unsigned)gy < 1024u && (unsigned)gx < 1024u)
            for (int d = 0; d < WP; ++d) mx = fmaxf(mx, vm[y * TM + xc + d]);
        if constexpr (sizeof(OT) == 2) mprev[i] = fbits(mx);
        else                           mprev[i] = mx;
    }
    __syncthreads();
}

__device__ __forceinline__ const void* maskChanPtr(const void* x, int n, bool isf) {
    return isf ? (const void*)((const float*)x + n * 2 * HW + HW)
               : (const void*)((const bf16*)x + n * 2 * HW + HW);
}

// ---------------- layer 1: cin=1, K=11 via MFMA implicit-GEMM ----------------
// Output NHWC: out[(n*HW + y*1024 + x)*16 + c], 32B-contiguous per quad.
__global__ __launch_bounds__(256) void convFirstM(
    const void* __restrict__ x, const bf16* __restrict__ wb1,
    const void* __restrict__ bias, bf16* __restrict__ out,
    float* statsCur, const float* flagp)
{
    constexpr int ST = 48, ROWS = 44, MT = 42;
    __shared__ alignas(16) short c0[ROWS * ST];
    __shared__ alignas(16) short c1[ROWS * ST + 2];
    __shared__ float smask[MT * MT];
    __shared__ float scs[32 * MT];
    __shared__ float sinv[1024];
    __shared__ float red[128];
    const bool isf = (*flagp > 0.5f);
    const int n = blockIdx.z;
    const int bx = blockIdx.x * 32, by = blockIdx.y * 32;
    const int tid = threadIdx.x, lane = tid & 63, wid = tid >> 6;
    const int nn = lane & 15, q = lane >> 4;

    // B fragments: lane = cout nn, k-block q; 6 K-steps of 32.
    s8v Bf[6];
    #pragma unroll
    for (int kb = 0; kb < 6; ++kb)
        Bf[kb] = *(const s8v*)(wb1 + ((kb * 4 + q) * 16 + nn) * 8);
    const float bv = ldv(bias, nn, isf);

    if (tid == 0) c1[0] = 0;

    // stage masked data (bf16, 2 shifted copies) + mask (fp32) tiles
    const int xoff = n * 2 * HW;
    for (int i = tid; i < ROWS * ST; i += 256) {
        int row = i / ST, col = i - row * ST;
        int yy = by - 5 + row, xx = bx - 5 + col;
        float d = 0.f, m = 0.f;
        if ((unsigned)yy < 1024u && (unsigned)xx < 1024u) {
            d = ldv(x, xoff + (yy << 10) + xx, isf);
            m = ldv(x, xoff + HW + (yy << 10) + xx, isf);
        }
        short b = fbits(d * m);
        c0[i] = b;
        c1[i + 1] = b;
        if (row < MT && col < MT) smask[row * MT + col] = m;
    }
    __syncthreads();

    // separable mask window sum: column pass
    for (int i = tid; i < 32 * MT; i += 256) {
        int r = i / MT, c = i - r * MT;
        float s = 0.f;
        #pragma unroll
        for (int dy = 0; dy < 11; ++dy) s += smask[(r + dy) * MT + c];
        scs[i] = s;
    }
    __syncthreads();
    // row pass -> per-pixel 121/(s+eps)
    for (int i = tid; i < 1024; i += 256) {
        int r = i >> 5, xc = i & 31;
        float s = 0.f;
        #pragma unroll
        for (int dx = 0; dx < 11; ++dx) s += scs[r * MT + xc + dx];
        sinv[i] = 121.f / (s + 1e-8f);
    }
    __syncthreads();

    // per-lane constant k-block decomposition: dy = kb*2 + dyq, dx0 = dxq
    const int dyq = q >> 1, dxq = (q & 1) << 3;
    const size_t nbase = (size_t)n * HW;
    float lsum = 0.f, lsq = 0.f;

    for (int mt = 0; mt < 16; ++mt) {
        int idx = wid * 16 + mt;
        int r = idx >> 1, g = idx & 1;
        int e = (r + dyq) * ST + (g << 4) + dxq + nn;   // elem idx, +96 per kb
        int s = e & 1;
        const unsigned* cp = s ? (const unsigned*)c1 : (const unsigned*)c0;
        int w = (e + s) >> 1;                            // word idx, +48 per kb
        f4v acc0 = {0.f, 0.f, 0.f, 0.f}, acc1 = {0.f, 0.f, 0.f, 0.f};
        __builtin_amdgcn_s_setprio(1);
        #pragma unroll
        for (int kb = 0; kb < 6; ++kb) {
            union { unsigned u[4]; s8v v; } A;
            A.u[0] = cp[w];
            A.u[1] = cp[w + 1];
            A.u[2] = cp[w + 2];
            A.u[3] = cp[w + 3];
            if (kb & 1)
                acc1 = __builtin_amdgcn_mfma_f32_16x16x32_bf16(A.v, Bf[kb], acc1, 0, 0, 0);
            else
                acc0 = __builtin_amdgcn_mfma_f32_16x16x32_bf16(A.v, Bf[kb], acc0, 0, 0, 0);
            w += ST;
        }
        __builtin_amdgcn_s_setprio(0);
        #pragma unroll
        for (int i2 = 0; i2 < 4; ++i2) {
            int px = (g << 4) + (q << 2) + i2;
            float y = fmaf(acc0[i2] + acc1[i2], sinv[(r << 5) + px], bv);
            out[((nbase + ((by + r) << 10) + bx + px) << 4) + nn] = f2b(y);
            lsum += y;
            lsq = fmaf(y, y, lsq);
        }
    }

    lsum += __shfl_xor(lsum, 16, 64);
    lsum += __shfl_xor(lsum, 32, 64);
    lsq  += __shfl_xor(lsq, 16, 64);
    lsq  += __shfl_xor(lsq, 32, 64);
    if (lane < 16) {
        red[wid * 32 + lane]      = lsum;
        red[wid * 32 + 16 + lane] = lsq;
    }
    __syncthreads();
    if (tid < 32) {
        float t = red[tid] + red[32 + tid] + red[64 + tid] + red[96 + tid];
        atomicAdd(&statsCur[tid], t);
    }
}

// ---------------- layers 2..5: MFMA implicit-GEMM, NHWC in/out ---------------
template <int K, int WP>
__global__ __launch_bounds__(256) void conv16m(
    const bf16* __restrict__ in, const void* __restrict__ x,
    const bf16* __restrict__ wtB, const float* statsPrev,
    const void* __restrict__ bias, bf16* __restrict__ out,
    float* statsCur, const float* flagp)
{
    constexpr int TK = 32 + K - 1;
    constexpr int TM = TK + WP - 1;
    constexpr int KK = K * K, NT = KK + 1, NK = NT / 2;
    constexpr int H2 = K / 2;
    __shared__ short sdatL[TK * TK * 8];
    __shared__ short sdatH[TK * TK * 8];
    __shared__ short mprevH[TK * TK];          // bf16 mask window (LDS diet)
    __shared__ float sinv[1024];
    __shared__ float red[128];
    __shared__ float sss[32];
    const bool isf = (*flagp > 0.5f);
    const int n = blockIdx.z;
    const int bx = blockIdx.x * 32, by = blockIdx.y * 32;
    const int tid = threadIdx.x, lane = tid & 63, wid = tid >> 6;

    if (tid < 16) { sss[tid] = statsPrev[32 + tid]; sss[16 + tid] = statsPrev[48 + tid]; }

    buildMaskTile<TM, TK, WP>(maskChanPtr(x, n, isf), isf,
                              (float*)sdatL, (float*)sdatH, mprevH, bx, by, tid);

    // separable sinv: col sums (into dead sdatH scratch) then row sums
    {
        float* cs = (float*)sdatH;          // 32*TK fp32 <= TK*TK*16 B
        for (int i = tid; i < 32 * TK; i += 256) {
            int r = i / TK, c = i - r * TK;
            float s = 0.f;
            #pragma unroll
            for (int dy = 0; dy < K; ++dy) s += bs2f(mprevH[(r + dy) * TK + c]);
            cs[i] = s;
        }
        __syncthreads();
        for (int i = tid; i < 1024; i += 256) {
            int r = i >> 5, xc = i & 31;
            float s = 0.f;
            #pragma unroll
            for (int dx = 0; dx < K; ++dx) s += cs[r * TK + xc + dx];
            sinv[i] = (float)KK / (s + 1e-8f);
        }
        __syncthreads();
    }

    const int nn = lane & 15, quad = lane >> 4, c0 = (quad & 1) * 8, tl = quad >> 1;
    s8v Bf[NK];
    #pragma unroll
    for (int kk = 0; kk < NK; ++kk) {
        int t = 2 * kk + tl;
        Bf[kk] = *(const s8v*)(wtB + ((t * 16 + nn) * 16 + c0));
    }

    // stage: NHWC vector loads (2x16B per pixel), transform, split L/H halves
    {
        const bf16* inb = in + ((size_t)n * HW << 4);
        for (int p = tid; p < TK * TK; p += 256) {
            int yy = by - H2 + p / TK, xx = bx - H2 + p % TK;
            s8v lo = {0,0,0,0,0,0,0,0}, hi = {0,0,0,0,0,0,0,0};
            if ((unsigned)yy < 1024u && (unsigned)xx < 1024u) {
                float mv = bs2f(mprevH[p]);
                const s8v* q = (const s8v*)(inb + ((size_t)((yy << 10) + xx) << 4));
                s8v rl = q[0], rh = q[1];
                #pragma unroll
                for (int c = 0; c < 8; ++c) {
                    float yv = bs2f(rl[c]);
                    lo[c] = fbits(fmaxf(fmaf(sss[c], yv, sss[16 + c]), 0.f) * mv);
                }
                #pragma unroll
                for (int c = 0; c < 8; ++c) {
                    float yv = bs2f(rh[c]);
                    hi[c] = fbits(fmaxf(fmaf(sss[c + 8], yv, sss[24 + c]), 0.f) * mv);
                }
            }
            ((s8v*)sdatL)[p] = lo;
            ((s8v*)sdatH)[p] = hi;
        }
    }
    __syncthreads();

    const float bv = ldv(bias, nn, isf);
    const s8v* Abase = (const s8v*)((quad & 1) ? sdatH : sdatL);
    const size_t nbase = (size_t)n * HW;
    float lsum = 0.f, lsq = 0.f;

    for (int mt = 0; mt < 16; ++mt) {
        int idx = wid * 16 + mt;
        int r = idx >> 1, xh = (idx & 1) << 4;
        int acol = xh + nn;
        f4v acc0 = {0.f, 0.f, 0.f, 0.f}, acc1 = {0.f, 0.f, 0.f, 0.f};
        __builtin_amdgcn_s_setprio(1);
        #pragma unroll
        for (int kk = 0; kk < NK; ++kk) {
            const int ta = (2 * kk < KK) ? 2 * kk : 0;
            const int tb = (2 * kk + 1 < KK) ? 2 * kk + 1 : 0;
            const int dya = ta / K, dxa = ta % K;
            const int dyb = tb / K, dxb = tb % K;
            int dy = tl ? dyb : dya;
            int dx = tl ? dxb : dxa;
            s8v a = Abase[(r + dy) * TK + acol + dx];
            if (kk & 1)
                acc1 = __builtin_amdgcn_mfma_f32_16x16x32_bf16(a, Bf[kk], acc1, 0, 0, 0);
            else
                acc0 = __builtin_amdgcn_mfma_f32_16x16x32_bf16(a, Bf[kk], acc0, 0, 0, 0);
        }
        __builtin_amdgcn_s_setprio(0);
        #pragma unroll
        for (int i = 0; i < 4; ++i) {
            float av = acc0[i] + acc1[i];
            int m = quad * 4 + i;
            float y = fmaf(av, sinv[r * 32 + xh + m], bv);
            out[((nbase + ((by + r) << 10) + bx + xh + m) << 4) + nn] = f2b(y);
            lsum += y;
            lsq = fmaf(y, y, lsq);
        }
    }

    lsum += __shfl_xor(lsum, 16, 64);
    lsum += __shfl_xor(lsum, 32, 64);
    lsq  += __shfl_xor(lsq, 16, 64);
    lsq  += __shfl_xor(lsq, 32, 64);
    if (lane < 16) {
        red[wid * 32 + lane]      = lsum;
        red[wid * 32 + 16 + lane] = lsq;
    }
    __syncthreads();
    if (tid < 32) {
        float t = red[tid] + red[32 + tid] + red[64 + tid] + red[96 + tid];
        atomicAdd(&statsCur[tid], t);
    }
}

// ---------------- layer 6: 1x1 conv to 1 channel (NHWC input) ----------------
__global__ __launch_bounds__(256) void layer6Kernel(
    const bf16* __restrict__ in, const void* __restrict__ x,
    const float* statsPrev, const void* __restrict__ w6,
    const void* __restrict__ b6, bf16* __restrict__ y6,
    float* statsCur, const float* flagp)
{
    constexpr int WP = 25, TM = 56, TK = 32;
    __shared__ float sm0[TM * TM];
    __shared__ float vm[TK * TM];
    __shared__ float m5[TK * TK];
    __shared__ float red[8];
    __shared__ float ssc[16], ssh[16];
    const bool isf = (*flagp > 0.5f);
    const int n = blockIdx.z;
    const int bx = blockIdx.x * 32, by = blockIdx.y * 32;
    const int tid = threadIdx.x;
    const int tx = tid & 31, ty0 = (tid >> 5) << 2;

    if (tid < 16) {
        ssc[tid] = statsPrev[32 + tid];
        ssh[tid] = statsPrev[48 + tid];
    }

    buildMaskTile<TM, TK, WP>(maskChanPtr(x, n, isf), isf, sm0, vm, m5, bx, by, tid);

    float wv[16];
    #pragma unroll
    for (int c = 0; c < 16; ++c) wv[c] = ldv(w6, c, isf);
    const float bias = ldv(b6, 0, isf);

    float lsum = 0.f, lsq = 0.f;
    #pragma unroll
    for (int p = 0; p < 4; ++p) {
        int yy = by + ty0 + p, xx = bx + tx;
        float m = m5[(ty0 + p) * TK + tx];
        const s8v* q = (const s8v*)(in + (((size_t)n * HW + (yy << 10) + xx) << 4));
        s8v rl = q[0], rh = q[1];
        float a = 0.f;
        #pragma unroll
        for (int c = 0; c < 8; ++c) {
            float h = fmaxf(fmaf(ssc[c], bs2f(rl[c]), ssh[c]), 0.f);
            a = fmaf(h, wv[c], a);
        }
        #pragma unroll
        for (int c = 0; c < 8; ++c) {
            float h = fmaxf(fmaf(ssc[c + 8], bs2f(rh[c]), ssh[c + 8]), 0.f);
            a = fmaf(h, wv[c + 8], a);
        }
        float yv = a * m / (m + 1e-8f) + bias;
        y6[n * HW + (yy << 10) + xx] = f2b(yv);
        lsum += yv;
        lsq = fmaf(yv, yv, lsq);
    }
    lsum = wave_reduce(lsum);
    lsq = wave_reduce(lsq);
    const int wid = tid >> 6, lane = tid & 63;
    if (lane == 0) { red[wid] = lsum; red[4 + wid] = lsq; }
    __syncthreads();
    if (tid == 0) atomicAdd(&statsCur[0],  red[0] + red[1] + red[2] + red[3]);
    if (tid == 1) atomicAdd(&statsCur[16], red[4] + red[5] + red[6] + red[7]);
}

// ---------------- helpers ----------------------------------------------------
__global__ void finalizeStats(float* stats, const void* __restrict__ g,
                              const void* __restrict__ bt, float alpha, int cout,
                              float* mirror, const float* flagp)
{
    const bool isf = (*flagp > 0.5f);
    int c = threadIdx.x;
    if (c < cout) {
        const float invN = 1.f / (4.f * HW);
        float meanp = stats[c] * invN;
        float varp  = fmaxf(stats[16 + c] * invN - meanp * meanp, 0.f);
        float var_t = varp / (alpha * alpha);
        float sct = ldv(g, c, isf) * rsqrtf(var_t + 1e-5f);
        float scp = sct / alpha;
        float shp = ldv(bt, c, isf) - scp * meanp;
        stats[32 + c] = scp;
        stats[48 + c] = shp;
        if (mirror) { mirror[2 * c] = scp; mirror[2 * c + 1] = shp; mirror[32] = isf ? 1.f : 0.f; }
    }
}

__global__ void finalOut(const bf16* __restrict__ y6, const float* mirror,
                         void* __restrict__ out)
{
    float sc = mirror[0], sh = mirror[1];
    const bool isf = (mirror[32] > 0.5f);
    for (int idx = blockIdx.x * 256 + threadIdx.x; idx < 4 * HW; idx += gridDim.x * 256) {
        float v = fmaf(b2f(y6[idx]), sc, sh);
        if (isf) ((float*)out)[idx] = v;
        else     ((bf16*)out)[idx] = f2b(v);
    }
}

__global__ void zeroStats(float* stats)
{
    int i = blockIdx.x * 256 + threadIdx.x;
    if (i < 384) stats[i] = 0.f;
}

__global__ void fillOut(void* out, const float* flagp, float v)
{
    const bool isf = (*flagp > 0.5f);
    for (int idx = blockIdx.x * 256 + threadIdx.x; idx < 4 * HW; idx += gridDim.x * 256) {
        if (isf) ((float*)out)[idx] = v;
        else     ((bf16*)out)[idx] = f2b(v);
    }
}

// ---------------- launch ------------------------------------------------------
extern "C" void kernel_launch(void* const* d_in, const int* in_sizes, int n_in,
                              void* d_out, int out_size, void* d_ws, size_t ws_size,
                              hipStream_t stream)
{
    const void* x = d_in[0];
    #define W(L)  ((const void*)d_in[1 + ((L) - 1) * 4])
    #define B(L)  ((const void*)d_in[2 + ((L) - 1) * 4])
    #define G(L)  ((const void*)d_in[3 + ((L) - 1) * 4])
    #define BT(L) ((const void*)d_in[4 + ((L) - 1) * 4])

    float* stats = (float*)d_out;
    const float* flagp = stats + 380;
    float* wt1 = stats + 384;
    bf16* wb1 = (bf16*)wt1;                  // 3072 bf16 = 6144 B < 7744 B slot
    bf16* wb2 = (bf16*)(wt1 + 1936);
    bf16* wb3 = wb2 + 50 * 256;
    bf16* wb4 = wb3 + 26 * 256;
    bf16* wb5 = wb4 + 10 * 256;
    const size_t need = 2 * (size_t)64 * HW * sizeof(bf16);

    zeroStats<<<2, 256, 0, stream>>>(stats);
    probeKernel<<<1, 256, 0, stream>>>((const unsigned short*)x, stats);

    if (ws_size < need) {
        fillOut<<<2048, 256, 0, stream>>>(d_out, flagp, 3.0f);
        return;
    }

    transposeW1<<<12, 256, 0, stream>>>(W(1), wb1, flagp);
    transposeWB<<<50, 256, 0, stream>>>(W(2), wb2, 49, 50, flagp);
    transposeWB<<<26, 256, 0, stream>>>(W(3), wb3, 25, 26, flagp);
    transposeWB<<<10, 256, 0, stream>>>(W(4), wb4, 9, 10, flagp);
    transposeWB<<<10, 256, 0, stream>>>(W(5), wb5, 9, 10, flagp);

    bf16* bufA = (bf16*)d_ws;
    bf16* bufB = bufA + 64 * HW;
    float* mirror = (float*)bufA;

    dim3 grid(32, 32, 4), block(256);

    convFirstM<<<grid, block, 0, stream>>>(x, wb1, B(1), bufA, stats + 0, flagp);
    finalizeStats<<<1, 64, 0, stream>>>(stats + 0, G(1), BT(1), 121.f, 16, nullptr, flagp);

    conv16m<7, 11><<<grid, block, 0, stream>>>(bufA, x, wb2, stats + 0, B(2), bufB, stats + 64, flagp);
    finalizeStats<<<1, 64, 0, stream>>>(stats + 64, G(2), BT(2), 49.f, 16, nullptr, flagp);

    conv16m<5, 17><<<grid, block, 0, stream>>>(bufB, x, wb3, stats + 64, B(3), bufA, stats + 128, flagp);
    finalizeStats<<<1, 64, 0, stream>>>(stats + 128, G(3), BT(3), 25.f, 16, nullptr, flagp);

    conv16m<3, 21><<<grid, block, 0, stream>>>(bufA, x, wb4, stats + 128, B(4), bufB, stats + 192, flagp);
    finalizeStats<<<1, 64, 0, stream>>>(stats + 192, G(4), BT(4), 9.f, 16, nullptr, flagp);

    conv16m<3, 23><<<grid, block, 0, stream>>>(bufB, x, wb5, stats + 192, B(5), bufA, stats + 256, flagp);
    finalizeStats<<<1, 64, 0, stream>>>(stats + 256, G(5), BT(5), 9.f, 16, nullptr, flagp);

    bf16* y6 = (bf16*)bufB;
    layer6Kernel<<<grid, block, 0, stream>>>(bufA, x, stats + 256, W(6), B(6), y6, stats + 320, flagp);
    finalizeStats<<<1, 64, 0, stream>>>(stats + 320, G(6), BT(6), 1.f, 1, mirror, flagp);
    finalOut<<<2048, 256, 0, stream>>>(y6, mirror, d_out);

    #undef W
    #undef B
    #undef G
    #undef BT
}

// Round 4
// 872.624 us; speedup vs baseline: 1.0229x; 1.0229x over previous
//
#include <hip/hip_runtime.h>
#include <hip/hip_bf16.h>

// SparseConvNet on MI355X — Round 14: real LDS diet, no setprio.
// R13 post-mortem: 54272 B LDS did NOT yield 3 blocks/CU (occupancy stayed
// 21.6%) -> driver reserves >1KB of the 160KB pool; and setprio around a
// ds_read-containing MFMA cluster REGRESSED (-15%, consistent with m190's
// lockstep-GEMM null/negative). R14 = R12 state + deeper diet past the
// cliff: mprev bf16 (2888B) + sinv bf16 (2048B) -> 52224 B, x3 = 156.7KB
// (7KB slack) -> 3 blocks/CU. No setprio. K=5 -> ~46.5KB, K=3 -> ~40KB.
// Predict conv16m<7,11>: occupancy ~30%, dur ~175us, total ~780us.
// absmax expected ~0.4 (sinv bf16 adds 0.4% on the norm factor).

#define HW (1024 * 1024)
typedef __hip_bfloat16 bf16;
typedef __attribute__((ext_vector_type(8))) short s8v;     // 8 bf16 = 4 VGPR
typedef __attribute__((ext_vector_type(4))) float f4v;     // MFMA acc

__device__ __forceinline__ float b2f(bf16 v) { return __bfloat162float(v); }
__device__ __forceinline__ bf16  f2b(float v) { return __float2bfloat16(v); }
__device__ __forceinline__ short fbits(float v) {
    bf16 t = f2b(v); short s; __builtin_memcpy(&s, &t, 2); return s;
}
__device__ __forceinline__ float bs2f(short s) {
    bf16 t; __builtin_memcpy(&t, &s, 2); return __bfloat162float(t);
}

__device__ __forceinline__ float ldv(const void* p, int i, bool isf) {
    return isf ? ((const float*)p)[i] : b2f(((const bf16*)p)[i]);
}

__device__ __forceinline__ float wave_reduce(float v) {
    #pragma unroll
    for (int off = 32; off > 0; off >>= 1)
        v += __shfl_down(v, off, 64);
    return v;
}

// ---------------- dtype probe: 1.0 = fp32 dataset, 0.0 = bf16 ----------------
__global__ void probeKernel(const unsigned short* __restrict__ xb,
                            float* __restrict__ stats)
{
    __shared__ int sbad;
    const int tid = threadIdx.x;
    if (tid == 0) sbad = 0;
    __syncthreads();
    int bad = 0;
    for (int i = tid; i < 4096; i += 256) {
        unsigned u = ((unsigned)xb[i]) << 16;
        float v = __uint_as_float(u);
        if (!(v >= 0.f && v < 1.f)) bad = 1;
    }
    if (bad) sbad = 1;
    __syncthreads();
    if (tid == 0) stats[380] = sbad ? 1.f : 0.f;
}

// ---- L1 weights for MFMA B: wb[((k8*16+co)*8)+j] = w[co][tap(k8*8+j)], bf16 -
// tap axis: k = dy*16 + dx, K = 192; dy in 0..11, dx in 0..15; pad -> 0.
__global__ void transposeW1(const void* __restrict__ w, bf16* __restrict__ wb,
                            const float* flagp)
{
    const bool isf = (*flagp > 0.5f);
    int j = blockIdx.x * 256 + threadIdx.x;
    if (j < 3072) {
        int col8 = j & 7;
        int co = (j >> 3) & 15;
        int k8 = j >> 7;
        int k = k8 * 8 + col8;
        int dy = k >> 4, dx = k & 15;
        float v = (dy < 11 && dx < 11) ? ldv(w, co * 121 + dy * 11 + dx, isf) : 0.f;
        wb[j] = f2b(v);
    }
}

// ---- L2-5 weights for MFMA B: wtB[((t*16+co)*16)+c] = w[co][c][t], bf16 -----
__global__ void transposeWB(const void* __restrict__ w, bf16* __restrict__ wtB,
                            int KK, int NT, const float* flagp)
{
    const bool isf = (*flagp > 0.5f);
    int j = blockIdx.x * 256 + threadIdx.x;
    if (j < NT * 256) {
        int t = j >> 8, co = (j >> 4) & 15, c = j & 15;
        float v = (t < KK) ? ldv(w, (co * 16 + c) * KK + t, isf) : 0.f;
        wtB[j] = f2b(v);
    }
}

// ---------------- composed mask tile (separable max over WP window) ----------
// OT = float (fp32 store) or short (bf16 store, for LDS-dieted conv16m).
template <int TM, int TK, int WP, typename OT>
__device__ __forceinline__ void buildMaskTile(
    const void* __restrict__ mask0, bool isf, float* sm0, float* vm,
    OT* mprev, int bx, int by, int tid)
{
    constexpr int H1 = (TM - 32) / 2;
    constexpr int H2 = (TK - 32) / 2;
    for (int i = tid; i < TM * TM; i += 256) {
        int yy = by - H1 + i / TM, xx = bx - H1 + i % TM;
        float m = 0.f;
        if ((unsigned)yy < 1024u && (unsigned)xx < 1024u)
            m = ldv(mask0, (yy << 10) + xx, isf);
        sm0[i] = m;
    }
    __syncthreads();
    for (int i = tid; i < TK * TM; i += 256) {
        int y = i / TM, xc = i % TM;
        float mx = 0.f;
        for (int d = 0; d < WP; ++d) mx = fmaxf(mx, sm0[(y + d) * TM + xc]);
        vm[i] = mx;
    }
    __syncthreads();
    for (int i = tid; i < TK * TK; i += 256) {
        int y = i / TK, xc = i % TK;
        int gy = by - H2 + y, gx = bx - H2 + xc;
        float mx = 0.f;
        if ((unsigned)gy < 1024u && (unsigned)gx < 1024u)
            for (int d = 0; d < WP; ++d) mx = fmaxf(mx, vm[y * TM + xc + d]);
        if constexpr (sizeof(OT) == 2) mprev[i] = fbits(mx);
        else                           mprev[i] = mx;
    }
    __syncthreads();
}

__device__ __forceinline__ const void* maskChanPtr(const void* x, int n, bool isf) {
    return isf ? (const void*)((const float*)x + n * 2 * HW + HW)
               : (const void*)((const bf16*)x + n * 2 * HW + HW);
}

// ---------------- layer 1: cin=1, K=11 via MFMA implicit-GEMM ----------------
// Output NHWC: out[(n*HW + y*1024 + x)*16 + c], 32B-contiguous per quad.
__global__ __launch_bounds__(256) void convFirstM(
    const void* __restrict__ x, const bf16* __restrict__ wb1,
    const void* __restrict__ bias, bf16* __restrict__ out,
    float* statsCur, const float* flagp)
{
    constexpr int ST = 48, ROWS = 44, MT = 42;
    __shared__ alignas(16) short c0[ROWS * ST];
    __shared__ alignas(16) short c1[ROWS * ST + 2];
    __shared__ float smask[MT * MT];
    __shared__ float scs[32 * MT];
    __shared__ float sinv[1024];
    __shared__ float red[128];
    const bool isf = (*flagp > 0.5f);
    const int n = blockIdx.z;
    const int bx = blockIdx.x * 32, by = blockIdx.y * 32;
    const int tid = threadIdx.x, lane = tid & 63, wid = tid >> 6;
    const int nn = lane & 15, q = lane >> 4;

    // B fragments: lane = cout nn, k-block q; 6 K-steps of 32.
    s8v Bf[6];
    #pragma unroll
    for (int kb = 0; kb < 6; ++kb)
        Bf[kb] = *(const s8v*)(wb1 + ((kb * 4 + q) * 16 + nn) * 8);
    const float bv = ldv(bias, nn, isf);

    if (tid == 0) c1[0] = 0;

    // stage masked data (bf16, 2 shifted copies) + mask (fp32) tiles
    const int xoff = n * 2 * HW;
    for (int i = tid; i < ROWS * ST; i += 256) {
        int row = i / ST, col = i - row * ST;
        int yy = by - 5 + row, xx = bx - 5 + col;
        float d = 0.f, m = 0.f;
        if ((unsigned)yy < 1024u && (unsigned)xx < 1024u) {
            d = ldv(x, xoff + (yy << 10) + xx, isf);
            m = ldv(x, xoff + HW + (yy << 10) + xx, isf);
        }
        short b = fbits(d * m);
        c0[i] = b;
        c1[i + 1] = b;
        if (row < MT && col < MT) smask[row * MT + col] = m;
    }
    __syncthreads();

    // separable mask window sum: column pass
    for (int i = tid; i < 32 * MT; i += 256) {
        int r = i / MT, c = i - r * MT;
        float s = 0.f;
        #pragma unroll
        for (int dy = 0; dy < 11; ++dy) s += smask[(r + dy) * MT + c];
        scs[i] = s;
    }
    __syncthreads();
    // row pass -> per-pixel 121/(s+eps)
    for (int i = tid; i < 1024; i += 256) {
        int r = i >> 5, xc = i & 31;
        float s = 0.f;
        #pragma unroll
        for (int dx = 0; dx < 11; ++dx) s += scs[r * MT + xc + dx];
        sinv[i] = 121.f / (s + 1e-8f);
    }
    __syncthreads();

    // per-lane constant k-block decomposition: dy = kb*2 + dyq, dx0 = dxq
    const int dyq = q >> 1, dxq = (q & 1) << 3;
    const size_t nbase = (size_t)n * HW;
    float lsum = 0.f, lsq = 0.f;

    for (int mt = 0; mt < 16; ++mt) {
        int idx = wid * 16 + mt;
        int r = idx >> 1, g = idx & 1;
        int e = (r + dyq) * ST + (g << 4) + dxq + nn;   // elem idx, +96 per kb
        int s = e & 1;
        const unsigned* cp = s ? (const unsigned*)c1 : (const unsigned*)c0;
        int w = (e + s) >> 1;                            // word idx, +48 per kb
        f4v acc0 = {0.f, 0.f, 0.f, 0.f}, acc1 = {0.f, 0.f, 0.f, 0.f};
        #pragma unroll
        for (int kb = 0; kb < 6; ++kb) {
            union { unsigned u[4]; s8v v; } A;
            A.u[0] = cp[w];
            A.u[1] = cp[w + 1];
            A.u[2] = cp[w + 2];
            A.u[3] = cp[w + 3];
            if (kb & 1)
                acc1 = __builtin_amdgcn_mfma_f32_16x16x32_bf16(A.v, Bf[kb], acc1, 0, 0, 0);
            else
                acc0 = __builtin_amdgcn_mfma_f32_16x16x32_bf16(A.v, Bf[kb], acc0, 0, 0, 0);
            w += ST;
        }
        #pragma unroll
        for (int i2 = 0; i2 < 4; ++i2) {
            int px = (g << 4) + (q << 2) + i2;
            float y = fmaf(acc0[i2] + acc1[i2], sinv[(r << 5) + px], bv);
            out[((nbase + ((by + r) << 10) + bx + px) << 4) + nn] = f2b(y);
            lsum += y;
            lsq = fmaf(y, y, lsq);
        }
    }

    lsum += __shfl_xor(lsum, 16, 64);
    lsum += __shfl_xor(lsum, 32, 64);
    lsq  += __shfl_xor(lsq, 16, 64);
    lsq  += __shfl_xor(lsq, 32, 64);
    if (lane < 16) {
        red[wid * 32 + lane]      = lsum;
        red[wid * 32 + 16 + lane] = lsq;
    }
    __syncthreads();
    if (tid < 32) {
        float t = red[tid] + red[32 + tid] + red[64 + tid] + red[96 + tid];
        atomicAdd(&statsCur[tid], t);
    }
}

// ---------------- layers 2..5: MFMA implicit-GEMM, NHWC in/out ---------------
template <int K, int WP>
__global__ __launch_bounds__(256) void conv16m(
    const bf16* __restrict__ in, const void* __restrict__ x,
    const bf16* __restrict__ wtB, const float* statsPrev,
    const void* __restrict__ bias, bf16* __restrict__ out,
    float* statsCur, const float* flagp)
{
    constexpr int TK = 32 + K - 1;
    constexpr int TM = TK + WP - 1;
    constexpr int KK = K * K, NT = KK + 1, NK = NT / 2;
    constexpr int H2 = K / 2;
    __shared__ short sdatL[TK * TK * 8];
    __shared__ short sdatH[TK * TK * 8];
    __shared__ short mprevH[TK * TK];          // bf16 mask window (LDS diet)
    __shared__ short sinvH[1024];              // bf16 norm factor (LDS diet)
    __shared__ float red[128];
    __shared__ float sss[32];
    const bool isf = (*flagp > 0.5f);
    const int n = blockIdx.z;
    const int bx = blockIdx.x * 32, by = blockIdx.y * 32;
    const int tid = threadIdx.x, lane = tid & 63, wid = tid >> 6;

    if (tid < 16) { sss[tid] = statsPrev[32 + tid]; sss[16 + tid] = statsPrev[48 + tid]; }

    buildMaskTile<TM, TK, WP>(maskChanPtr(x, n, isf), isf,
                              (float*)sdatL, (float*)sdatH, mprevH, bx, by, tid);

    // separable sinv: col sums (into dead sdatH scratch) then row sums
    {
        float* cs = (float*)sdatH;          // 32*TK fp32 <= TK*TK*16 B
        for (int i = tid; i < 32 * TK; i += 256) {
            int r = i / TK, c = i - r * TK;
            float s = 0.f;
            #pragma unroll
            for (int dy = 0; dy < K; ++dy) s += bs2f(mprevH[(r + dy) * TK + c]);
            cs[i] = s;
        }
        __syncthreads();
        for (int i = tid; i < 1024; i += 256) {
            int r = i >> 5, xc = i & 31;
            float s = 0.f;
            #pragma unroll
            for (int dx = 0; dx < K; ++dx) s += cs[r * TK + xc + dx];
            sinvH[i] = fbits((float)KK / (s + 1e-8f));
        }
        __syncthreads();
    }

    const int nn = lane & 15, quad = lane >> 4, c0 = (quad & 1) * 8, tl = quad >> 1;
    s8v Bf[NK];
    #pragma unroll
    for (int kk = 0; kk < NK; ++kk) {
        int t = 2 * kk + tl;
        Bf[kk] = *(const s8v*)(wtB + ((t * 16 + nn) * 16 + c0));
    }

    // stage: NHWC vector loads (2x16B per pixel), transform, split L/H halves
    {
        const bf16* inb = in + ((size_t)n * HW << 4);
        for (int p = tid; p < TK * TK; p += 256) {
            int yy = by - H2 + p / TK, xx = bx - H2 + p % TK;
            s8v lo = {0,0,0,0,0,0,0,0}, hi = {0,0,0,0,0,0,0,0};
            if ((unsigned)yy < 1024u && (unsigned)xx < 1024u) {
                float mv = bs2f(mprevH[p]);
                const s8v* q = (const s8v*)(inb + ((size_t)((yy << 10) + xx) << 4));
                s8v rl = q[0], rh = q[1];
                #pragma unroll
                for (int c = 0; c < 8; ++c) {
                    float yv = bs2f(rl[c]);
                    lo[c] = fbits(fmaxf(fmaf(sss[c], yv, sss[16 + c]), 0.f) * mv);
                }
                #pragma unroll
                for (int c = 0; c < 8; ++c) {
                    float yv = bs2f(rh[c]);
                    hi[c] = fbits(fmaxf(fmaf(sss[c + 8], yv, sss[24 + c]), 0.f) * mv);
                }
            }
            ((s8v*)sdatL)[p] = lo;
            ((s8v*)sdatH)[p] = hi;
        }
    }
    __syncthreads();

    const float bv = ldv(bias, nn, isf);
    const s8v* Abase = (const s8v*)((quad & 1) ? sdatH : sdatL);
    const size_t nbase = (size_t)n * HW;
    float lsum = 0.f, lsq = 0.f;

    for (int mt = 0; mt < 16; ++mt) {
        int idx = wid * 16 + mt;
        int r = idx >> 1, xh = (idx & 1) << 4;
        int acol = xh + nn;
        f4v acc0 = {0.f, 0.f, 0.f, 0.f}, acc1 = {0.f, 0.f, 0.f, 0.f};
        #pragma unroll
        for (int kk = 0; kk < NK; ++kk) {
            const int ta = (2 * kk < KK) ? 2 * kk : 0;
            const int tb = (2 * kk + 1 < KK) ? 2 * kk + 1 : 0;
            const int dya = ta / K, dxa = ta % K;
            const int dyb = tb / K, dxb = tb % K;
            int dy = tl ? dyb : dya;
            int dx = tl ? dxb : dxa;
            s8v a = Abase[(r + dy) * TK + acol + dx];
            if (kk & 1)
                acc1 = __builtin_amdgcn_mfma_f32_16x16x32_bf16(a, Bf[kk], acc1, 0, 0, 0);
            else
                acc0 = __builtin_amdgcn_mfma_f32_16x16x32_bf16(a, Bf[kk], acc0, 0, 0, 0);
        }
        #pragma unroll
        for (int i = 0; i < 4; ++i) {
            float av = acc0[i] + acc1[i];
            int m = quad * 4 + i;
            float y = fmaf(av, bs2f(sinvH[r * 32 + xh + m]), bv);
            out[((nbase + ((by + r) << 10) + bx + xh + m) << 4) + nn] = f2b(y);
            lsum += y;
            lsq = fmaf(y, y, lsq);
        }
    }

    lsum += __shfl_xor(lsum, 16, 64);
    lsum += __shfl_xor(lsum, 32, 64);
    lsq  += __shfl_xor(lsq, 16, 64);
    lsq  += __shfl_xor(lsq, 32, 64);
    if (lane < 16) {
        red[wid * 32 + lane]      = lsum;
        red[wid * 32 + 16 + lane] = lsq;
    }
    __syncthreads();
    if (tid < 32) {
        float t = red[tid] + red[32 + tid] + red[64 + tid] + red[96 + tid];
        atomicAdd(&statsCur[tid], t);
    }
}

// ---------------- layer 6: 1x1 conv to 1 channel (NHWC input) ----------------
__global__ __launch_bounds__(256) void layer6Kernel(
    const bf16* __restrict__ in, const void* __restrict__ x,
    const float* statsPrev, const void* __restrict__ w6,
    const void* __restrict__ b6, bf16* __restrict__ y6,
    float* statsCur, const float* flagp)
{
    constexpr int WP = 25, TM = 56, TK = 32;
    __shared__ float sm0[TM * TM];
    __shared__ float vm[TK * TM];
    __shared__ float m5[TK * TK];
    __shared__ float red[8];
    __shared__ float ssc[16], ssh[16];
    const bool isf = (*flagp > 0.5f);
    const int n = blockIdx.z;
    const int bx = blockIdx.x * 32, by = blockIdx.y * 32;
    const int tid = threadIdx.x;
    const int tx = tid & 31, ty0 = (tid >> 5) << 2;

    if (tid < 16) {
        ssc[tid] = statsPrev[32 + tid];
        ssh[tid] = statsPrev[48 + tid];
    }

    buildMaskTile<TM, TK, WP>(maskChanPtr(x, n, isf), isf, sm0, vm, m5, bx, by, tid);

    float wv[16];
    #pragma unroll
    for (int c = 0; c < 16; ++c) wv[c] = ldv(w6, c, isf);
    const float bias = ldv(b6, 0, isf);

    float lsum = 0.f, lsq = 0.f;
    #pragma unroll
    for (int p = 0; p < 4; ++p) {
        int yy = by + ty0 + p, xx = bx + tx;
        float m = m5[(ty0 + p) * TK + tx];
        const s8v* q = (const s8v*)(in + (((size_t)n * HW + (yy << 10) + xx) << 4));
        s8v rl = q[0], rh = q[1];
        float a = 0.f;
        #pragma unroll
        for (int c = 0; c < 8; ++c) {
            float h = fmaxf(fmaf(ssc[c], bs2f(rl[c]), ssh[c]), 0.f);
            a = fmaf(h, wv[c], a);
        }
        #pragma unroll
        for (int c = 0; c < 8; ++c) {
            float h = fmaxf(fmaf(ssc[c + 8], bs2f(rh[c]), ssh[c + 8]), 0.f);
            a = fmaf(h, wv[c + 8], a);
        }
        float yv = a * m / (m + 1e-8f) + bias;
        y6[n * HW + (yy << 10) + xx] = f2b(yv);
        lsum += yv;
        lsq = fmaf(yv, yv, lsq);
    }
    lsum = wave_reduce(lsum);
    lsq = wave_reduce(lsq);
    const int wid = tid >> 6, lane = tid & 63;
    if (lane == 0) { red[wid] = lsum; red[4 + wid] = lsq; }
    __syncthreads();
    if (tid == 0) atomicAdd(&statsCur[0],  red[0] + red[1] + red[2] + red[3]);
    if (tid == 1) atomicAdd(&statsCur[16], red[4] + red[5] + red[6] + red[7]);
}

// ---------------- helpers ----------------------------------------------------
__global__ void finalizeStats(float* stats, const void* __restrict__ g,
                              const void* __restrict__ bt, float alpha, int cout,
                              float* mirror, const float* flagp)
{
    const bool isf = (*flagp > 0.5f);
    int c = threadIdx.x;
    if (c < cout) {
        const float invN = 1.f / (4.f * HW);
        float meanp = stats[c] * invN;
        float varp  = fmaxf(stats[16 + c] * invN - meanp * meanp, 0.f);
        float var_t = varp / (alpha * alpha);
        float sct = ldv(g, c, isf) * rsqrtf(var_t + 1e-5f);
        float scp = sct / alpha;
        float shp = ldv(bt, c, isf) - scp * meanp;
        stats[32 + c] = scp;
        stats[48 + c] = shp;
        if (mirror) { mirror[2 * c] = scp; mirror[2 * c + 1] = shp; mirror[32] = isf ? 1.f : 0.f; }
    }
}

__global__ void finalOut(const bf16* __restrict__ y6, const float* mirror,
                         void* __restrict__ out)
{
    float sc = mirror[0], sh = mirror[1];
    const bool isf = (mirror[32] > 0.5f);
    for (int idx = blockIdx.x * 256 + threadIdx.x; idx < 4 * HW; idx += gridDim.x * 256) {
        float v = fmaf(b2f(y6[idx]), sc, sh);
        if (isf) ((float*)out)[idx] = v;
        else     ((bf16*)out)[idx] = f2b(v);
    }
}

__global__ void zeroStats(float* stats)
{
    int i = blockIdx.x * 256 + threadIdx.x;
    if (i < 384) stats[i] = 0.f;
}

__global__ void fillOut(void* out, const float* flagp, float v)
{
    const bool isf = (*flagp > 0.5f);
    for (int idx = blockIdx.x * 256 + threadIdx.x; idx < 4 * HW; idx += gridDim.x * 256) {
        if (isf) ((float*)out)[idx] = v;
        else     ((bf16*)out)[idx] = f2b(v);
    }
}

// ---------------- launch ------------------------------------------------------
extern "C" void kernel_launch(void* const* d_in, const int* in_sizes, int n_in,
                              void* d_out, int out_size, void* d_ws, size_t ws_size,
                              hipStream_t stream)
{
    const void* x = d_in[0];
    #define W(L)  ((const void*)d_in[1 + ((L) - 1) * 4])
    #define B(L)  ((const void*)d_in[2 + ((L) - 1) * 4])
    #define G(L)  ((const void*)d_in[3 + ((L) - 1) * 4])
    #define BT(L) ((const void*)d_in[4 + ((L) - 1) * 4])

    float* stats = (float*)d_out;
    const float* flagp = stats + 380;
    float* wt1 = stats + 384;
    bf16* wb1 = (bf16*)wt1;                  // 3072 bf16 = 6144 B < 7744 B slot
    bf16* wb2 = (bf16*)(wt1 + 1936);
    bf16* wb3 = wb2 + 50 * 256;
    bf16* wb4 = wb3 + 26 * 256;
    bf16* wb5 = wb4 + 10 * 256;
    const size_t need = 2 * (size_t)64 * HW * sizeof(bf16);

    zeroStats<<<2, 256, 0, stream>>>(stats);
    probeKernel<<<1, 256, 0, stream>>>((const unsigned short*)x, stats);

    if (ws_size < need) {
        fillOut<<<2048, 256, 0, stream>>>(d_out, flagp, 3.0f);
        return;
    }

    transposeW1<<<12, 256, 0, stream>>>(W(1), wb1, flagp);
    transposeWB<<<50, 256, 0, stream>>>(W(2), wb2, 49, 50, flagp);
    transposeWB<<<26, 256, 0, stream>>>(W(3), wb3, 25, 26, flagp);
    transposeWB<<<10, 256, 0, stream>>>(W(4), wb4, 9, 10, flagp);
    transposeWB<<<10, 256, 0, stream>>>(W(5), wb5, 9, 10, flagp);

    bf16* bufA = (bf16*)d_ws;
    bf16* bufB = bufA + 64 * HW;
    float* mirror = (float*)bufA;

    dim3 grid(32, 32, 4), block(256);

    convFirstM<<<grid, block, 0, stream>>>(x, wb1, B(1), bufA, stats + 0, flagp);
    finalizeStats<<<1, 64, 0, stream>>>(stats + 0, G(1), BT(1), 121.f, 16, nullptr, flagp);

    conv16m<7, 11><<<grid, block, 0, stream>>>(bufA, x, wb2, stats + 0, B(2), bufB, stats + 64, flagp);
    finalizeStats<<<1, 64, 0, stream>>>(stats + 64, G(2), BT(2), 49.f, 16, nullptr, flagp);

    conv16m<5, 17><<<grid, block, 0, stream>>>(bufB, x, wb3, stats + 64, B(3), bufA, stats + 128, flagp);
    finalizeStats<<<1, 64, 0, stream>>>(stats + 128, G(3), BT(3), 25.f, 16, nullptr, flagp);

    conv16m<3, 21><<<grid, block, 0, stream>>>(bufA, x, wb4, stats + 128, B(4), bufB, stats + 192, flagp);
    finalizeStats<<<1, 64, 0, stream>>>(stats + 192, G(4), BT(4), 9.f, 16, nullptr, flagp);

    conv16m<3, 23><<<grid, block, 0, stream>>>(bufB, x, wb5, stats + 192, B(5), bufA, stats + 256, flagp);
    finalizeStats<<<1, 64, 0, stream>>>(stats + 256, G(5), BT(5), 9.f, 16, nullptr, flagp);

    bf16* y6 = (bf16*)bufB;
    layer6Kernel<<<grid, block, 0, stream>>>(bufA, x, stats + 256, W(6), B(6), y6, stats + 320, flagp);
    finalizeStats<<<1, 64, 0, stream>>>(stats + 320, G(6), BT(6), 1.f, 1, mirror, flagp);
    finalOut<<<2048, 256, 0, stream>>>(y6, mirror, d_out);

    #undef W
    #undef B
    #undef G
    #undef BT
}

// Round 6
// 838.823 us; speedup vs baseline: 1.0641x; 1.0403x over previous
//
#include <hip/hip_runtime.h>
#include <hip/hip_bf16.h>

// SparseConvNet on MI355X — Round 16: resubmit of R15 (container infra fail).
// R15 never ran ("MI355X container failed twice" = broker error, no kernel
// signal). Kernel unchanged from R15: revert to R12 state + resident
// B-fragments via __launch_bounds__(256,2) on conv16m.
// Theory: Bf[25] needs 100 VGPR but VGPR_Count=88 -> compiler remats ~400
// B-fragment VMEM loads inside the mt hot loop at 2 waves/SIMD. Occupancy
// is LDS-bound (2 blocks/CU, usable LDS pool < nominal 160KB per R13/R14),
// so VGPR up to 256 is free.
// Predict conv16m<7,11>: VGPR ~160-200, dur ~170us, total ~790us.

#define HW (1024 * 1024)
typedef __hip_bfloat16 bf16;
typedef __attribute__((ext_vector_type(8))) short s8v;     // 8 bf16 = 4 VGPR
typedef __attribute__((ext_vector_type(4))) float f4v;     // MFMA acc

__device__ __forceinline__ float b2f(bf16 v) { return __bfloat162float(v); }
__device__ __forceinline__ bf16  f2b(float v) { return __float2bfloat16(v); }
__device__ __forceinline__ short fbits(float v) {
    bf16 t = f2b(v); short s; __builtin_memcpy(&s, &t, 2); return s;
}
__device__ __forceinline__ float bs2f(short s) {
    bf16 t; __builtin_memcpy(&t, &s, 2); return __bfloat162float(t);
}

__device__ __forceinline__ float ldv(const void* p, int i, bool isf) {
    return isf ? ((const float*)p)[i] : b2f(((const bf16*)p)[i]);
}

__device__ __forceinline__ float wave_reduce(float v) {
    #pragma unroll
    for (int off = 32; off > 0; off >>= 1)
        v += __shfl_down(v, off, 64);
    return v;
}

// ---------------- dtype probe: 1.0 = fp32 dataset, 0.0 = bf16 ----------------
__global__ void probeKernel(const unsigned short* __restrict__ xb,
                            float* __restrict__ stats)
{
    __shared__ int sbad;
    const int tid = threadIdx.x;
    if (tid == 0) sbad = 0;
    __syncthreads();
    int bad = 0;
    for (int i = tid; i < 4096; i += 256) {
        unsigned u = ((unsigned)xb[i]) << 16;
        float v = __uint_as_float(u);
        if (!(v >= 0.f && v < 1.f)) bad = 1;
    }
    if (bad) sbad = 1;
    __syncthreads();
    if (tid == 0) stats[380] = sbad ? 1.f : 0.f;
}

// ---- L1 weights for MFMA B: wb[((k8*16+co)*8)+j] = w[co][tap(k8*8+j)], bf16 -
// tap axis: k = dy*16 + dx, K = 192; dy in 0..11, dx in 0..15; pad -> 0.
__global__ void transposeW1(const void* __restrict__ w, bf16* __restrict__ wb,
                            const float* flagp)
{
    const bool isf = (*flagp > 0.5f);
    int j = blockIdx.x * 256 + threadIdx.x;
    if (j < 3072) {
        int col8 = j & 7;
        int co = (j >> 3) & 15;
        int k8 = j >> 7;
        int k = k8 * 8 + col8;
        int dy = k >> 4, dx = k & 15;
        float v = (dy < 11 && dx < 11) ? ldv(w, co * 121 + dy * 11 + dx, isf) : 0.f;
        wb[j] = f2b(v);
    }
}

// ---- L2-5 weights for MFMA B: wtB[((t*16+co)*16)+c] = w[co][c][t], bf16 -----
__global__ void transposeWB(const void* __restrict__ w, bf16* __restrict__ wtB,
                            int KK, int NT, const float* flagp)
{
    const bool isf = (*flagp > 0.5f);
    int j = blockIdx.x * 256 + threadIdx.x;
    if (j < NT * 256) {
        int t = j >> 8, co = (j >> 4) & 15, c = j & 15;
        float v = (t < KK) ? ldv(w, (co * 16 + c) * KK + t, isf) : 0.f;
        wtB[j] = f2b(v);
    }
}

// ---------------- composed mask tile (separable max over WP window) ----------
template <int TM, int TK, int WP>
__device__ __forceinline__ void buildMaskTile(
    const void* __restrict__ mask0, bool isf, float* sm0, float* vm,
    float* mprev, int bx, int by, int tid)
{
    constexpr int H1 = (TM - 32) / 2;
    constexpr int H2 = (TK - 32) / 2;
    for (int i = tid; i < TM * TM; i += 256) {
        int yy = by - H1 + i / TM, xx = bx - H1 + i % TM;
        float m = 0.f;
        if ((unsigned)yy < 1024u && (unsigned)xx < 1024u)
            m = ldv(mask0, (yy << 10) + xx, isf);
        sm0[i] = m;
    }
    __syncthreads();
    for (int i = tid; i < TK * TM; i += 256) {
        int y = i / TM, xc = i % TM;
        float mx = 0.f;
        for (int d = 0; d < WP; ++d) mx = fmaxf(mx, sm0[(y + d) * TM + xc]);
        vm[i] = mx;
    }
    __syncthreads();
    for (int i = tid; i < TK * TK; i += 256) {
        int y = i / TK, xc = i % TK;
        int gy = by - H2 + y, gx = bx - H2 + xc;
        float mx = 0.f;
        if ((unsigned)gy < 1024u && (unsigned)gx < 1024u)
            for (int d = 0; d < WP; ++d) mx = fmaxf(mx, vm[y * TM + xc + d]);
        mprev[i] = mx;
    }
    __syncthreads();
}

__device__ __forceinline__ const void* maskChanPtr(const void* x, int n, bool isf) {
    return isf ? (const void*)((const float*)x + n * 2 * HW + HW)
               : (const void*)((const bf16*)x + n * 2 * HW + HW);
}

// ---------------- layer 1: cin=1, K=11 via MFMA implicit-GEMM ----------------
// Output NHWC: out[(n*HW + y*1024 + x)*16 + c], 32B-contiguous per quad.
__global__ __launch_bounds__(256) void convFirstM(
    const void* __restrict__ x, const bf16* __restrict__ wb1,
    const void* __restrict__ bias, bf16* __restrict__ out,
    float* statsCur, const float* flagp)
{
    constexpr int ST = 48, ROWS = 44, MT = 42;
    __shared__ alignas(16) short c0[ROWS * ST];
    __shared__ alignas(16) short c1[ROWS * ST + 2];
    __shared__ float smask[MT * MT];
    __shared__ float scs[32 * MT];
    __shared__ float sinv[1024];
    __shared__ float red[128];
    const bool isf = (*flagp > 0.5f);
    const int n = blockIdx.z;
    const int bx = blockIdx.x * 32, by = blockIdx.y * 32;
    const int tid = threadIdx.x, lane = tid & 63, wid = tid >> 6;
    const int nn = lane & 15, q = lane >> 4;

    // B fragments: lane = cout nn, k-block q; 6 K-steps of 32.
    s8v Bf[6];
    #pragma unroll
    for (int kb = 0; kb < 6; ++kb)
        Bf[kb] = *(const s8v*)(wb1 + ((kb * 4 + q) * 16 + nn) * 8);
    const float bv = ldv(bias, nn, isf);

    if (tid == 0) c1[0] = 0;

    // stage masked data (bf16, 2 shifted copies) + mask (fp32) tiles
    const int xoff = n * 2 * HW;
    for (int i = tid; i < ROWS * ST; i += 256) {
        int row = i / ST, col = i - row * ST;
        int yy = by - 5 + row, xx = bx - 5 + col;
        float d = 0.f, m = 0.f;
        if ((unsigned)yy < 1024u && (unsigned)xx < 1024u) {
            d = ldv(x, xoff + (yy << 10) + xx, isf);
            m = ldv(x, xoff + HW + (yy << 10) + xx, isf);
        }
        short b = fbits(d * m);
        c0[i] = b;
        c1[i + 1] = b;
        if (row < MT && col < MT) smask[row * MT + col] = m;
    }
    __syncthreads();

    // separable mask window sum: column pass
    for (int i = tid; i < 32 * MT; i += 256) {
        int r = i / MT, c = i - r * MT;
        float s = 0.f;
        #pragma unroll
        for (int dy = 0; dy < 11; ++dy) s += smask[(r + dy) * MT + c];
        scs[i] = s;
    }
    __syncthreads();
    // row pass -> per-pixel 121/(s+eps)
    for (int i = tid; i < 1024; i += 256) {
        int r = i >> 5, xc = i & 31;
        float s = 0.f;
        #pragma unroll
        for (int dx = 0; dx < 11; ++dx) s += scs[r * MT + xc + dx];
        sinv[i] = 121.f / (s + 1e-8f);
    }
    __syncthreads();

    // per-lane constant k-block decomposition: dy = kb*2 + dyq, dx0 = dxq
    const int dyq = q >> 1, dxq = (q & 1) << 3;
    const size_t nbase = (size_t)n * HW;
    float lsum = 0.f, lsq = 0.f;

    for (int mt = 0; mt < 16; ++mt) {
        int idx = wid * 16 + mt;
        int r = idx >> 1, g = idx & 1;
        int e = (r + dyq) * ST + (g << 4) + dxq + nn;   // elem idx, +96 per kb
        int s = e & 1;
        const unsigned* cp = s ? (const unsigned*)c1 : (const unsigned*)c0;
        int w = (e + s) >> 1;                            // word idx, +48 per kb
        f4v acc0 = {0.f, 0.f, 0.f, 0.f}, acc1 = {0.f, 0.f, 0.f, 0.f};
        #pragma unroll
        for (int kb = 0; kb < 6; ++kb) {
            union { unsigned u[4]; s8v v; } A;
            A.u[0] = cp[w];
            A.u[1] = cp[w + 1];
            A.u[2] = cp[w + 2];
            A.u[3] = cp[w + 3];
            if (kb & 1)
                acc1 = __builtin_amdgcn_mfma_f32_16x16x32_bf16(A.v, Bf[kb], acc1, 0, 0, 0);
            else
                acc0 = __builtin_amdgcn_mfma_f32_16x16x32_bf16(A.v, Bf[kb], acc0, 0, 0, 0);
            w += ST;
        }
        #pragma unroll
        for (int i2 = 0; i2 < 4; ++i2) {
            int px = (g << 4) + (q << 2) + i2;
            float y = fmaf(acc0[i2] + acc1[i2], sinv[(r << 5) + px], bv);
            out[((nbase + ((by + r) << 10) + bx + px) << 4) + nn] = f2b(y);
            lsum += y;
            lsq = fmaf(y, y, lsq);
        }
    }

    lsum += __shfl_xor(lsum, 16, 64);
    lsum += __shfl_xor(lsum, 32, 64);
    lsq  += __shfl_xor(lsq, 16, 64);
    lsq  += __shfl_xor(lsq, 32, 64);
    if (lane < 16) {
        red[wid * 32 + lane]      = lsum;
        red[wid * 32 + 16 + lane] = lsq;
    }
    __syncthreads();
    if (tid < 32) {
        float t = red[tid] + red[32 + tid] + red[64 + tid] + red[96 + tid];
        atomicAdd(&statsCur[tid], t);
    }
}

// ---------------- layers 2..5: MFMA implicit-GEMM, NHWC in/out ---------------
// __launch_bounds__(256, 2): occupancy is LDS-bound at 2 blocks/CU, so allow
// the allocator up to ~256 VGPR -> B fragments (Bf[NK], up to 100 VGPR) stay
// resident instead of being rematerialized as ~400 VMEM loads in the mt loop.
template <int K, int WP>
__global__ __launch_bounds__(256, 2) void conv16m(
    const bf16* __restrict__ in, const void* __restrict__ x,
    const bf16* __restrict__ wtB, const float* statsPrev,
    const void* __restrict__ bias, bf16* __restrict__ out,
    float* statsCur, const float* flagp)
{
    constexpr int TK = 32 + K - 1;
    constexpr int TM = TK + WP - 1;
    constexpr int KK = K * K, NT = KK + 1, NK = NT / 2;
    constexpr int H2 = K / 2;
    __shared__ short sdatL[TK * TK * 8];
    __shared__ short sdatH[TK * TK * 8];
    __shared__ float mprev[TK * TK];
    __shared__ float sinv[1024];
    __shared__ float red[128];
    __shared__ float sss[32];
    const bool isf = (*flagp > 0.5f);
    const int n = blockIdx.z;
    const int bx = blockIdx.x * 32, by = blockIdx.y * 32;
    const int tid = threadIdx.x, lane = tid & 63, wid = tid >> 6;

    if (tid < 16) { sss[tid] = statsPrev[32 + tid]; sss[16 + tid] = statsPrev[48 + tid]; }

    buildMaskTile<TM, TK, WP>(maskChanPtr(x, n, isf), isf,
                              (float*)sdatL, (float*)sdatH, mprev, bx, by, tid);

    // separable sinv: col sums (into dead sdatH scratch) then row sums
    {
        float* cs = (float*)sdatH;          // 32*TK fp32 <= TK*TK*16 B
        for (int i = tid; i < 32 * TK; i += 256) {
            int r = i / TK, c = i - r * TK;
            float s = 0.f;
            #pragma unroll
            for (int dy = 0; dy < K; ++dy) s += mprev[(r + dy) * TK + c];
            cs[i] = s;
        }
        __syncthreads();
        for (int i = tid; i < 1024; i += 256) {
            int r = i >> 5, xc = i & 31;
            float s = 0.f;
            #pragma unroll
            for (int dx = 0; dx < K; ++dx) s += cs[r * TK + xc + dx];
            sinv[i] = (float)KK / (s + 1e-8f);
        }
        __syncthreads();
    }

    const int nn = lane & 15, quad = lane >> 4, c0 = (quad & 1) * 8, tl = quad >> 1;
    s8v Bf[NK];
    #pragma unroll
    for (int kk = 0; kk < NK; ++kk) {
        int t = 2 * kk + tl;
        Bf[kk] = *(const s8v*)(wtB + ((t * 16 + nn) * 16 + c0));
    }

    // stage: NHWC vector loads (2x16B per pixel), transform, split L/H halves
    {
        const bf16* inb = in + ((size_t)n * HW << 4);
        for (int p = tid; p < TK * TK; p += 256) {
            int yy = by - H2 + p / TK, xx = bx - H2 + p % TK;
            s8v lo = {0,0,0,0,0,0,0,0}, hi = {0,0,0,0,0,0,0,0};
            if ((unsigned)yy < 1024u && (unsigned)xx < 1024u) {
                float mv = mprev[p];
                const s8v* q = (const s8v*)(inb + ((size_t)((yy << 10) + xx) << 4));
                s8v rl = q[0], rh = q[1];
                #pragma unroll
                for (int c = 0; c < 8; ++c) {
                    float yv = bs2f(rl[c]);
                    lo[c] = fbits(fmaxf(fmaf(sss[c], yv, sss[16 + c]), 0.f) * mv);
                }
                #pragma unroll
                for (int c = 0; c < 8; ++c) {
                    float yv = bs2f(rh[c]);
                    hi[c] = fbits(fmaxf(fmaf(sss[c + 8], yv, sss[24 + c]), 0.f) * mv);
                }
            }
            ((s8v*)sdatL)[p] = lo;
            ((s8v*)sdatH)[p] = hi;
        }
    }
    __syncthreads();

    const float bv = ldv(bias, nn, isf);
    const s8v* Abase = (const s8v*)((quad & 1) ? sdatH : sdatL);
    const size_t nbase = (size_t)n * HW;
    float lsum = 0.f, lsq = 0.f;

    for (int mt = 0; mt < 16; ++mt) {
        int idx = wid * 16 + mt;
        int r = idx >> 1, xh = (idx & 1) << 4;
        int acol = xh + nn;
        f4v acc0 = {0.f, 0.f, 0.f, 0.f}, acc1 = {0.f, 0.f, 0.f, 0.f};
        #pragma unroll
        for (int kk = 0; kk < NK; ++kk) {
            const int ta = (2 * kk < KK) ? 2 * kk : 0;
            const int tb = (2 * kk + 1 < KK) ? 2 * kk + 1 : 0;
            const int dya = ta / K, dxa = ta % K;
            const int dyb = tb / K, dxb = tb % K;
            int dy = tl ? dyb : dya;
            int dx = tl ? dxb : dxa;
            s8v a = Abase[(r + dy) * TK + acol + dx];
            if (kk & 1)
                acc1 = __builtin_amdgcn_mfma_f32_16x16x32_bf16(a, Bf[kk], acc1, 0, 0, 0);
            else
                acc0 = __builtin_amdgcn_mfma_f32_16x16x32_bf16(a, Bf[kk], acc0, 0, 0, 0);
        }
        #pragma unroll
        for (int i = 0; i < 4; ++i) {
            float av = acc0[i] + acc1[i];
            int m = quad * 4 + i;
            float y = fmaf(av, sinv[r * 32 + xh + m], bv);
            out[((nbase + ((by + r) << 10) + bx + xh + m) << 4) + nn] = f2b(y);
            lsum += y;
            lsq = fmaf(y, y, lsq);
        }
    }

    lsum += __shfl_xor(lsum, 16, 64);
    lsum += __shfl_xor(lsum, 32, 64);
    lsq  += __shfl_xor(lsq, 16, 64);
    lsq  += __shfl_xor(lsq, 32, 64);
    if (lane < 16) {
        red[wid * 32 + lane]      = lsum;
        red[wid * 32 + 16 + lane] = lsq;
    }
    __syncthreads();
    if (tid < 32) {
        float t = red[tid] + red[32 + tid] + red[64 + tid] + red[96 + tid];
        atomicAdd(&statsCur[tid], t);
    }
}

// ---------------- layer 6: 1x1 conv to 1 channel (NHWC input) ----------------
__global__ __launch_bounds__(256) void layer6Kernel(
    const bf16* __restrict__ in, const void* __restrict__ x,
    const float* statsPrev, const void* __restrict__ w6,
    const void* __restrict__ b6, bf16* __restrict__ y6,
    float* statsCur, const float* flagp)
{
    constexpr int WP = 25, TM = 56, TK = 32;
    __shared__ float sm0[TM * TM];
    __shared__ float vm[TK * TM];
    __shared__ float m5[TK * TK];
    __shared__ float red[8];
    __shared__ float ssc[16], ssh[16];
    const bool isf = (*flagp > 0.5f);
    const int n = blockIdx.z;
    const int bx = blockIdx.x * 32, by = blockIdx.y * 32;
    const int tid = threadIdx.x;
    const int tx = tid & 31, ty0 = (tid >> 5) << 2;

    if (tid < 16) {
        ssc[tid] = statsPrev[32 + tid];
        ssh[tid] = statsPrev[48 + tid];
    }

    buildMaskTile<TM, TK, WP>(maskChanPtr(x, n, isf), isf, sm0, vm, m5, bx, by, tid);

    float wv[16];
    #pragma unroll
    for (int c = 0; c < 16; ++c) wv[c] = ldv(w6, c, isf);
    const float bias = ldv(b6, 0, isf);

    float lsum = 0.f, lsq = 0.f;
    #pragma unroll
    for (int p = 0; p < 4; ++p) {
        int yy = by + ty0 + p, xx = bx + tx;
        float m = m5[(ty0 + p) * TK + tx];
        const s8v* q = (const s8v*)(in + (((size_t)n * HW + (yy << 10) + xx) << 4));
        s8v rl = q[0], rh = q[1];
        float a = 0.f;
        #pragma unroll
        for (int c = 0; c < 8; ++c) {
            float h = fmaxf(fmaf(ssc[c], bs2f(rl[c]), ssh[c]), 0.f);
            a = fmaf(h, wv[c], a);
        }
        #pragma unroll
        for (int c = 0; c < 8; ++c) {
            float h = fmaxf(fmaf(ssc[c + 8], bs2f(rh[c]), ssh[c + 8]), 0.f);
            a = fmaf(h, wv[c + 8], a);
        }
        float yv = a * m / (m + 1e-8f) + bias;
        y6[n * HW + (yy << 10) + xx] = f2b(yv);
        lsum += yv;
        lsq = fmaf(yv, yv, lsq);
    }
    lsum = wave_reduce(lsum);
    lsq = wave_reduce(lsq);
    const int wid = tid >> 6, lane = tid & 63;
    if (lane == 0) { red[wid] = lsum; red[4 + wid] = lsq; }
    __syncthreads();
    if (tid == 0) atomicAdd(&statsCur[0],  red[0] + red[1] + red[2] + red[3]);
    if (tid == 1) atomicAdd(&statsCur[16], red[4] + red[5] + red[6] + red[7]);
}

// ---------------- helpers ----------------------------------------------------
__global__ void finalizeStats(float* stats, const void* __restrict__ g,
                              const void* __restrict__ bt, float alpha, int cout,
                              float* mirror, const float* flagp)
{
    const bool isf = (*flagp > 0.5f);
    int c = threadIdx.x;
    if (c < cout) {
        const float invN = 1.f / (4.f * HW);
        float meanp = stats[c] * invN;
        float varp  = fmaxf(stats[16 + c] * invN - meanp * meanp, 0.f);
        float var_t = varp / (alpha * alpha);
        float sct = ldv(g, c, isf) * rsqrtf(var_t + 1e-5f);
        float scp = sct / alpha;
        float shp = ldv(bt, c, isf) - scp * meanp;
        stats[32 + c] = scp;
        stats[48 + c] = shp;
        if (mirror) { mirror[2 * c] = scp; mirror[2 * c + 1] = shp; mirror[32] = isf ? 1.f : 0.f; }
    }
}

__global__ void finalOut(const bf16* __restrict__ y6, const float* mirror,
                         void* __restrict__ out)
{
    float sc = mirror[0], sh = mirror[1];
    const bool isf = (mirror[32] > 0.5f);
    for (int idx = blockIdx.x * 256 + threadIdx.x; idx < 4 * HW; idx += gridDim.x * 256) {
        float v = fmaf(b2f(y6[idx]), sc, sh);
        if (isf) ((float*)out)[idx] = v;
        else     ((bf16*)out)[idx] = f2b(v);
    }
}

__global__ void zeroStats(float* stats)
{
    int i = blockIdx.x * 256 + threadIdx.x;
    if (i < 384) stats[i] = 0.f;
}

__global__ void fillOut(void* out, const float* flagp, float v)
{
    const bool isf = (*flagp > 0.5f);
    for (int idx = blockIdx.x * 256 + threadIdx.x; idx < 4 * HW; idx += gridDim.x * 256) {
        if (isf) ((float*)out)[idx] = v;
        else     ((bf16*)out)[idx] = f2b(v);
    }
}

// ---------------- launch ------------------------------------------------------
extern "C" void kernel_launch(void* const* d_in, const int* in_sizes, int n_in,
                              void* d_out, int out_size, void* d_ws, size_t ws_size,
                              hipStream_t stream)
{
    const void* x = d_in[0];
    #define W(L)  ((const void*)d_in[1 + ((L) - 1) * 4])
    #define B(L)  ((const void*)d_in[2 + ((L) - 1) * 4])
    #define G(L)  ((const void*)d_in[3 + ((L) - 1) * 4])
    #define BT(L) ((const void*)d_in[4 + ((L) - 1) * 4])

    float* stats = (float*)d_out;
    const float* flagp = stats + 380;
    float* wt1 = stats + 384;
    bf16* wb1 = (bf16*)wt1;                  // 3072 bf16 = 6144 B < 7744 B slot
    bf16* wb2 = (bf16*)(wt1 + 1936);
    bf16* wb3 = wb2 + 50 * 256;
    bf16* wb4 = wb3 + 26 * 256;
    bf16* wb5 = wb4 + 10 * 256;
    const size_t need = 2 * (size_t)64 * HW * sizeof(bf16);

    zeroStats<<<2, 256, 0, stream>>>(stats);
    probeKernel<<<1, 256, 0, stream>>>((const unsigned short*)x, stats);

    if (ws_size < need) {
        fillOut<<<2048, 256, 0, stream>>>(d_out, flagp, 3.0f);
        return;
    }

    transposeW1<<<12, 256, 0, stream>>>(W(1), wb1, flagp);
    transposeWB<<<50, 256, 0, stream>>>(W(2), wb2, 49, 50, flagp);
    transposeWB<<<26, 256, 0, stream>>>(W(3), wb3, 25, 26, flagp);
    transposeWB<<<10, 256, 0, stream>>>(W(4), wb4, 9, 10, flagp);
    transposeWB<<<10, 256, 0, stream>>>(W(5), wb5, 9, 10, flagp);

    bf16* bufA = (bf16*)d_ws;
    bf16* bufB = bufA + 64 * HW;
    float* mirror = (float*)bufA;

    dim3 grid(32, 32, 4), block(256);

    convFirstM<<<grid, block, 0, stream>>>(x, wb1, B(1), bufA, stats + 0, flagp);
    finalizeStats<<<1, 64, 0, stream>>>(stats + 0, G(1), BT(1), 121.f, 16, nullptr, flagp);

    conv16m<7, 11><<<grid, block, 0, stream>>>(bufA, x, wb2, stats + 0, B(2), bufB, stats + 64, flagp);
    finalizeStats<<<1, 64, 0, stream>>>(stats + 64, G(2), BT(2), 49.f, 16, nullptr, flagp);

    conv16m<5, 17><<<grid, block, 0, stream>>>(bufB, x, wb3, stats + 64, B(3), bufA, stats + 128, flagp);
    finalizeStats<<<1, 64, 0, stream>>>(stats + 128, G(3), BT(3), 25.f, 16, nullptr, flagp);

    conv16m<3, 21><<<grid, block, 0, stream>>>(bufA, x, wb4, stats + 128, B(4), bufB, stats + 192, flagp);
    finalizeStats<<<1, 64, 0, stream>>>(stats + 192, G(4), BT(4), 9.f, 16, nullptr, flagp);

    conv16m<3, 23><<<grid, block, 0, stream>>>(bufB, x, wb5, stats + 192, B(5), bufA, stats + 256, flagp);
    finalizeStats<<<1, 64, 0, stream>>>(stats + 256, G(5), BT(5), 9.f, 16, nullptr, flagp);

    bf16* y6 = (bf16*)bufB;
    layer6Kernel<<<grid, block, 0, stream>>>(bufA, x, stats + 256, W(6), B(6), y6, stats + 320, flagp);
    finalizeStats<<<1, 64, 0, stream>>>(stats + 320, G(6), BT(6), 1.f, 1, mirror, flagp);
    finalOut<<<2048, 256, 0, stream>>>(y6, mirror, d_out);

    #undef W
    #undef B
    #undef G
    #undef BT
}

// Round 7
// 803.543 us; speedup vs baseline: 1.1108x; 1.0439x over previous
//
#include <hip/hip_runtime.h>
#include <hip/hip_bf16.h>

// SparseConvNet on MI355X — Round 17: sliding-window A-reuse in conv16m.
// R16 falsified B-remat theory (launch_bounds(256,2) -> VGPR stayed 88, dur
// unchanged). Cost model: conv16m<7,11> is LDS-READ-bound: 1600 b128/block
// x ~12cyc = 128us + 45us conflicts = 81% of 213us. The A-traffic is 7x
// redundant: frag(r, dy,dx) == frag(r+1, dy-1,dx). Fix: wave slides over
// absolute rows ar=0..8+K-2; reads each frag ONCE (2 halves) per dx-pair,
// feeds all valid dy via acc[ar-dy] (fully unrolled -> static reg indexing).
// dx padded to DXP (8/6/4): zero weights, +12-20% MFMA, A-reads /4 (448->112
// per wave). Pad s8v slot at TK*TK zeroed (pad-col reads stay finite).
// Predict conv16m<7,11> ~130us, conflicts 2.8e7 -> ~1e7, total ~670us.

#define HW (1024 * 1024)
typedef __hip_bfloat16 bf16;
typedef __attribute__((ext_vector_type(8))) short s8v;     // 8 bf16 = 4 VGPR
typedef __attribute__((ext_vector_type(4))) float f4v;     // MFMA acc

__device__ __forceinline__ float b2f(bf16 v) { return __bfloat162float(v); }
__device__ __forceinline__ bf16  f2b(float v) { return __float2bfloat16(v); }
__device__ __forceinline__ short fbits(float v) {
    bf16 t = f2b(v); short s; __builtin_memcpy(&s, &t, 2); return s;
}
__device__ __forceinline__ float bs2f(short s) {
    bf16 t; __builtin_memcpy(&t, &s, 2); return __bfloat162float(t);
}

__device__ __forceinline__ float ldv(const void* p, int i, bool isf) {
    return isf ? ((const float*)p)[i] : b2f(((const bf16*)p)[i]);
}

__device__ __forceinline__ float wave_reduce(float v) {
    #pragma unroll
    for (int off = 32; off > 0; off >>= 1)
        v += __shfl_down(v, off, 64);
    return v;
}

// ---------------- dtype probe: 1.0 = fp32 dataset, 0.0 = bf16 ----------------
__global__ void probeKernel(const unsigned short* __restrict__ xb,
                            float* __restrict__ stats)
{
    __shared__ int sbad;
    const int tid = threadIdx.x;
    if (tid == 0) sbad = 0;
    __syncthreads();
    int bad = 0;
    for (int i = tid; i < 4096; i += 256) {
        unsigned u = ((unsigned)xb[i]) << 16;
        float v = __uint_as_float(u);
        if (!(v >= 0.f && v < 1.f)) bad = 1;
    }
    if (bad) sbad = 1;
    __syncthreads();
    if (tid == 0) stats[380] = sbad ? 1.f : 0.f;
}

// ---- L1 weights for MFMA B: wb[((k8*16+co)*8)+j] = w[co][tap(k8*8+j)], bf16 -
// tap axis: k = dy*16 + dx, K = 192; dy in 0..11, dx in 0..15; pad -> 0.
__global__ void transposeW1(const void* __restrict__ w, bf16* __restrict__ wb,
                            const float* flagp)
{
    const bool isf = (*flagp > 0.5f);
    int j = blockIdx.x * 256 + threadIdx.x;
    if (j < 3072) {
        int col8 = j & 7;
        int co = (j >> 3) & 15;
        int k8 = j >> 7;
        int k = k8 * 8 + col8;
        int dy = k >> 4, dx = k & 15;
        float v = (dy < 11 && dx < 11) ? ldv(w, co * 121 + dy * 11 + dx, isf) : 0.f;
        wb[j] = f2b(v);
    }
}

// ---- L2-5 weights, dx-padded layout: t = dy*DXP + dx (dx >= K -> 0) --------
// wtB[((t*16+co)*16)+c] = w[co][c][dy*K+dx]
__global__ void transposeWB(const void* __restrict__ w, bf16* __restrict__ wtB,
                            int K, int DXP, const float* flagp)
{
    const bool isf = (*flagp > 0.5f);
    int NT = K * DXP;
    int j = blockIdx.x * 256 + threadIdx.x;
    if (j < NT * 256) {
        int t = j >> 8, co = (j >> 4) & 15, c = j & 15;
        int dy = t / DXP, dx = t % DXP;
        float v = (dx < K) ? ldv(w, (co * 16 + c) * (K * K) + dy * K + dx, isf) : 0.f;
        wtB[j] = f2b(v);
    }
}

// ---------------- composed mask tile (separable max over WP window) ----------
template <int TM, int TK, int WP>
__device__ __forceinline__ void buildMaskTile(
    const void* __restrict__ mask0, bool isf, float* sm0, float* vm,
    float* mprev, int bx, int by, int tid)
{
    constexpr int H1 = (TM - 32) / 2;
    constexpr int H2 = (TK - 32) / 2;
    for (int i = tid; i < TM * TM; i += 256) {
        int yy = by - H1 + i / TM, xx = bx - H1 + i % TM;
        float m = 0.f;
        if ((unsigned)yy < 1024u && (unsigned)xx < 1024u)
            m = ldv(mask0, (yy << 10) + xx, isf);
        sm0[i] = m;
    }
    __syncthreads();
    for (int i = tid; i < TK * TM; i += 256) {
        int y = i / TM, xc = i % TM;
        float mx = 0.f;
        for (int d = 0; d < WP; ++d) mx = fmaxf(mx, sm0[(y + d) * TM + xc]);
        vm[i] = mx;
    }
    __syncthreads();
    for (int i = tid; i < TK * TK; i += 256) {
        int y = i / TK, xc = i % TK;
        int gy = by - H2 + y, gx = bx - H2 + xc;
        float mx = 0.f;
        if ((unsigned)gy < 1024u && (unsigned)gx < 1024u)
            for (int d = 0; d < WP; ++d) mx = fmaxf(mx, vm[y * TM + xc + d]);
        mprev[i] = mx;
    }
    __syncthreads();
}

__device__ __forceinline__ const void* maskChanPtr(const void* x, int n, bool isf) {
    return isf ? (const void*)((const float*)x + n * 2 * HW + HW)
               : (const void*)((const bf16*)x + n * 2 * HW + HW);
}

// ---------------- layer 1: cin=1, K=11 via MFMA implicit-GEMM ----------------
// Output NHWC: out[(n*HW + y*1024 + x)*16 + c], 32B-contiguous per quad.
__global__ __launch_bounds__(256) void convFirstM(
    const void* __restrict__ x, const bf16* __restrict__ wb1,
    const void* __restrict__ bias, bf16* __restrict__ out,
    float* statsCur, const float* flagp)
{
    constexpr int ST = 48, ROWS = 44, MT = 42;
    __shared__ alignas(16) short c0[ROWS * ST];
    __shared__ alignas(16) short c1[ROWS * ST + 2];
    __shared__ float smask[MT * MT];
    __shared__ float scs[32 * MT];
    __shared__ float sinv[1024];
    __shared__ float red[128];
    const bool isf = (*flagp > 0.5f);
    const int n = blockIdx.z;
    const int bx = blockIdx.x * 32, by = blockIdx.y * 32;
    const int tid = threadIdx.x, lane = tid & 63, wid = tid >> 6;
    const int nn = lane & 15, q = lane >> 4;

    // B fragments: lane = cout nn, k-block q; 6 K-steps of 32.
    s8v Bf[6];
    #pragma unroll
    for (int kb = 0; kb < 6; ++kb)
        Bf[kb] = *(const s8v*)(wb1 + ((kb * 4 + q) * 16 + nn) * 8);
    const float bv = ldv(bias, nn, isf);

    if (tid == 0) c1[0] = 0;

    // stage masked data (bf16, 2 shifted copies) + mask (fp32) tiles
    const int xoff = n * 2 * HW;
    for (int i = tid; i < ROWS * ST; i += 256) {
        int row = i / ST, col = i - row * ST;
        int yy = by - 5 + row, xx = bx - 5 + col;
        float d = 0.f, m = 0.f;
        if ((unsigned)yy < 1024u && (unsigned)xx < 1024u) {
            d = ldv(x, xoff + (yy << 10) + xx, isf);
            m = ldv(x, xoff + HW + (yy << 10) + xx, isf);
        }
        short b = fbits(d * m);
        c0[i] = b;
        c1[i + 1] = b;
        if (row < MT && col < MT) smask[row * MT + col] = m;
    }
    __syncthreads();

    // separable mask window sum: column pass
    for (int i = tid; i < 32 * MT; i += 256) {
        int r = i / MT, c = i - r * MT;
        float s = 0.f;
        #pragma unroll
        for (int dy = 0; dy < 11; ++dy) s += smask[(r + dy) * MT + c];
        scs[i] = s;
    }
    __syncthreads();
    // row pass -> per-pixel 121/(s+eps)
    for (int i = tid; i < 1024; i += 256) {
        int r = i >> 5, xc = i & 31;
        float s = 0.f;
        #pragma unroll
        for (int dx = 0; dx < 11; ++dx) s += scs[r * MT + xc + dx];
        sinv[i] = 121.f / (s + 1e-8f);
    }
    __syncthreads();

    // per-lane constant k-block decomposition: dy = kb*2 + dyq, dx0 = dxq
    const int dyq = q >> 1, dxq = (q & 1) << 3;
    const size_t nbase = (size_t)n * HW;
    float lsum = 0.f, lsq = 0.f;

    for (int mt = 0; mt < 16; ++mt) {
        int idx = wid * 16 + mt;
        int r = idx >> 1, g = idx & 1;
        int e = (r + dyq) * ST + (g << 4) + dxq + nn;   // elem idx, +96 per kb
        int s = e & 1;
        const unsigned* cp = s ? (const unsigned*)c1 : (const unsigned*)c0;
        int w = (e + s) >> 1;                            // word idx, +48 per kb
        f4v acc0 = {0.f, 0.f, 0.f, 0.f}, acc1 = {0.f, 0.f, 0.f, 0.f};
        #pragma unroll
        for (int kb = 0; kb < 6; ++kb) {
            union { unsigned u[4]; s8v v; } A;
            A.u[0] = cp[w];
            A.u[1] = cp[w + 1];
            A.u[2] = cp[w + 2];
            A.u[3] = cp[w + 3];
            if (kb & 1)
                acc1 = __builtin_amdgcn_mfma_f32_16x16x32_bf16(A.v, Bf[kb], acc1, 0, 0, 0);
            else
                acc0 = __builtin_amdgcn_mfma_f32_16x16x32_bf16(A.v, Bf[kb], acc0, 0, 0, 0);
            w += ST;
        }
        #pragma unroll
        for (int i2 = 0; i2 < 4; ++i2) {
            int px = (g << 4) + (q << 2) + i2;
            float y = fmaf(acc0[i2] + acc1[i2], sinv[(r << 5) + px], bv);
            out[((nbase + ((by + r) << 10) + bx + px) << 4) + nn] = f2b(y);
            lsum += y;
            lsq = fmaf(y, y, lsq);
        }
    }

    lsum += __shfl_xor(lsum, 16, 64);
    lsum += __shfl_xor(lsum, 32, 64);
    lsq  += __shfl_xor(lsq, 16, 64);
    lsq  += __shfl_xor(lsq, 32, 64);
    if (lane < 16) {
        red[wid * 32 + lane]      = lsum;
        red[wid * 32 + 16 + lane] = lsq;
    }
    __syncthreads();
    if (tid < 32) {
        float t = red[tid] + red[32 + tid] + red[64 + tid] + red[96 + tid];
        atomicAdd(&statsCur[tid], t);
    }
}

// ---------------- layers 2..5: MFMA implicit-GEMM, sliding-window A-reuse ----
// Wave owns 8 output rows x 32 cols. Iterate absolute row ar = 0..8+K-2:
// read each A-fragment ONCE per dx-pair j (2 halves), feed all valid dy via
// acc[ar-dy] (all loops unrolled -> static register indexing). dx padded to
// DXP with zero weights.
template <int K, int WP, int DXP>
__global__ __launch_bounds__(256, 2) void conv16m(
    const bf16* __restrict__ in, const void* __restrict__ x,
    const bf16* __restrict__ wtB, const float* statsPrev,
    const void* __restrict__ bias, bf16* __restrict__ out,
    float* statsCur, const float* flagp)
{
    constexpr int TK = 32 + K - 1;
    constexpr int TM = TK + WP - 1;
    constexpr int NJ = DXP / 2;            // dx-pairs per dy row
    constexpr int NK = K * NJ;             // B fragments
    constexpr int KK = K * K;
    constexpr int H2 = K / 2;
    __shared__ short sdatL[(TK * TK + 1) * 8];   // +1 pad s8v (zeroed)
    __shared__ short sdatH[(TK * TK + 1) * 8];
    __shared__ float mprev[TK * TK];
    __shared__ float sinv[1024];
    __shared__ float red[128];
    __shared__ float sss[32];
    const bool isf = (*flagp > 0.5f);
    const int n = blockIdx.z;
    const int bx = blockIdx.x * 32, by = blockIdx.y * 32;
    const int tid = threadIdx.x, lane = tid & 63, wid = tid >> 6;

    if (tid < 16) { sss[tid] = statsPrev[32 + tid]; sss[16 + tid] = statsPrev[48 + tid]; }

    buildMaskTile<TM, TK, WP>(maskChanPtr(x, n, isf), isf,
                              (float*)sdatL, (float*)sdatH, mprev, bx, by, tid);

    // separable sinv: col sums (into dead sdatH scratch) then row sums
    {
        float* cs = (float*)sdatH;          // 32*TK fp32 <= TK*TK*16 B
        for (int i = tid; i < 32 * TK; i += 256) {
            int r = i / TK, c = i - r * TK;
            float s = 0.f;
            #pragma unroll
            for (int dy = 0; dy < K; ++dy) s += mprev[(r + dy) * TK + c];
            cs[i] = s;
        }
        __syncthreads();
        for (int i = tid; i < 1024; i += 256) {
            int r = i >> 5, xc = i & 31;
            float s = 0.f;
            #pragma unroll
            for (int dx = 0; dx < K; ++dx) s += cs[r * TK + xc + dx];
            sinv[i] = (float)KK / (s + 1e-8f);
        }
        __syncthreads();
    }

    const int nn = lane & 15, quad = lane >> 4, c0 = (quad & 1) * 8, tl = quad >> 1;
    s8v Bf[NK];
    #pragma unroll
    for (int kk = 0; kk < NK; ++kk) {
        int dy = kk / NJ, jj = kk % NJ;
        int t = dy * DXP + 2 * jj + tl;
        Bf[kk] = *(const s8v*)(wtB + ((t * 16 + nn) * 16 + c0));
    }

    // stage: NHWC vector loads (2x16B per pixel), transform, split L/H halves
    {
        const bf16* inb = in + ((size_t)n * HW << 4);
        for (int p = tid; p < TK * TK; p += 256) {
            int yy = by - H2 + p / TK, xx = bx - H2 + p % TK;
            s8v lo = {0,0,0,0,0,0,0,0}, hi = {0,0,0,0,0,0,0,0};
            if ((unsigned)yy < 1024u && (unsigned)xx < 1024u) {
                float mv = mprev[p];
                const s8v* q = (const s8v*)(inb + ((size_t)((yy << 10) + xx) << 4));
                s8v rl = q[0], rh = q[1];
                #pragma unroll
                for (int c = 0; c < 8; ++c) {
                    float yv = bs2f(rl[c]);
                    lo[c] = fbits(fmaxf(fmaf(sss[c], yv, sss[16 + c]), 0.f) * mv);
                }
                #pragma unroll
                for (int c = 0; c < 8; ++c) {
                    float yv = bs2f(rh[c]);
                    hi[c] = fbits(fmaxf(fmaf(sss[c + 8], yv, sss[24 + c]), 0.f) * mv);
                }
            }
            ((s8v*)sdatL)[p] = lo;
            ((s8v*)sdatH)[p] = hi;
        }
        if (tid == 0) {                      // zero the pad slot (index TK*TK)
            s8v z = {0,0,0,0,0,0,0,0};
            ((s8v*)sdatL)[TK * TK] = z;
            ((s8v*)sdatH)[TK * TK] = z;
        }
    }
    __syncthreads();

    const float bv = ldv(bias, nn, isf);
    const s8v* Abase = (const s8v*)((quad & 1) ? sdatH : sdatL);
    const size_t nbase = (size_t)n * HW;
    const int r0 = wid * 8;

    f4v acc[8][2];
    #pragma unroll
    for (int rr = 0; rr < 8; ++rr) {
        acc[rr][0] = f4v{0.f, 0.f, 0.f, 0.f};
        acc[rr][1] = f4v{0.f, 0.f, 0.f, 0.f};
    }

    #pragma unroll
    for (int ar = 0; ar < 8 + K - 1; ++ar) {
        #pragma unroll
        for (int j = 0; j < NJ; ++j) {
            const int base = (r0 + ar) * TK + nn + 2 * j + tl;
            const s8v F0 = Abase[base];
            const s8v F1 = Abase[base + 16];
            #pragma unroll
            for (int dy = 0; dy < K; ++dy) {
                if (ar - dy >= 0 && ar - dy < 8) {
                    acc[ar - dy][0] = __builtin_amdgcn_mfma_f32_16x16x32_bf16(
                        F0, Bf[dy * NJ + j], acc[ar - dy][0], 0, 0, 0);
                    acc[ar - dy][1] = __builtin_amdgcn_mfma_f32_16x16x32_bf16(
                        F1, Bf[dy * NJ + j], acc[ar - dy][1], 0, 0, 0);
                }
            }
        }
    }

    float lsum = 0.f, lsq = 0.f;
    #pragma unroll
    for (int rr = 0; rr < 8; ++rr) {
        const int r = r0 + rr;
        #pragma unroll
        for (int h = 0; h < 2; ++h) {
            const int xh = h << 4;
            #pragma unroll
            for (int i = 0; i < 4; ++i) {
                int m = quad * 4 + i;
                float y = fmaf(acc[rr][h][i], sinv[r * 32 + xh + m], bv);
                out[((nbase + ((by + r) << 10) + bx + xh + m) << 4) + nn] = f2b(y);
                lsum += y;
                lsq = fmaf(y, y, lsq);
            }
        }
    }

    lsum += __shfl_xor(lsum, 16, 64);
    lsum += __shfl_xor(lsum, 32, 64);
    lsq  += __shfl_xor(lsq, 16, 64);
    lsq  += __shfl_xor(lsq, 32, 64);
    if (lane < 16) {
        red[wid * 32 + lane]      = lsum;
        red[wid * 32 + 16 + lane] = lsq;
    }
    __syncthreads();
    if (tid < 32) {
        float t = red[tid] + red[32 + tid] + red[64 + tid] + red[96 + tid];
        atomicAdd(&statsCur[tid], t);
    }
}

// ---------------- layer 6: 1x1 conv to 1 channel (NHWC input) ----------------
__global__ __launch_bounds__(256) void layer6Kernel(
    const bf16* __restrict__ in, const void* __restrict__ x,
    const float* statsPrev, const void* __restrict__ w6,
    const void* __restrict__ b6, bf16* __restrict__ y6,
    float* statsCur, const float* flagp)
{
    constexpr int WP = 25, TM = 56, TK = 32;
    __shared__ float sm0[TM * TM];
    __shared__ float vm[TK * TM];
    __shared__ float m5[TK * TK];
    __shared__ float red[8];
    __shared__ float ssc[16], ssh[16];
    const bool isf = (*flagp > 0.5f);
    const int n = blockIdx.z;
    const int bx = blockIdx.x * 32, by = blockIdx.y * 32;
    const int tid = threadIdx.x;
    const int tx = tid & 31, ty0 = (tid >> 5) << 2;

    if (tid < 16) {
        ssc[tid] = statsPrev[32 + tid];
        ssh[tid] = statsPrev[48 + tid];
    }

    buildMaskTile<TM, TK, WP>(maskChanPtr(x, n, isf), isf, sm0, vm, m5, bx, by, tid);

    float wv[16];
    #pragma unroll
    for (int c = 0; c < 16; ++c) wv[c] = ldv(w6, c, isf);
    const float bias = ldv(b6, 0, isf);

    float lsum = 0.f, lsq = 0.f;
    #pragma unroll
    for (int p = 0; p < 4; ++p) {
        int yy = by + ty0 + p, xx = bx + tx;
        float m = m5[(ty0 + p) * TK + tx];
        const s8v* q = (const s8v*)(in + (((size_t)n * HW + (yy << 10) + xx) << 4));
        s8v rl = q[0], rh = q[1];
        float a = 0.f;
        #pragma unroll
        for (int c = 0; c < 8; ++c) {
            float h = fmaxf(fmaf(ssc[c], bs2f(rl[c]), ssh[c]), 0.f);
            a = fmaf(h, wv[c], a);
        }
        #pragma unroll
        for (int c = 0; c < 8; ++c) {
            float h = fmaxf(fmaf(ssc[c + 8], bs2f(rh[c]), ssh[c + 8]), 0.f);
            a = fmaf(h, wv[c + 8], a);
        }
        float yv = a * m / (m + 1e-8f) + bias;
        y6[n * HW + (yy << 10) + xx] = f2b(yv);
        lsum += yv;
        lsq = fmaf(yv, yv, lsq);
    }
    lsum = wave_reduce(lsum);
    lsq = wave_reduce(lsq);
    const int wid = tid >> 6, lane = tid & 63;
    if (lane == 0) { red[wid] = lsum; red[4 + wid] = lsq; }
    __syncthreads();
    if (tid == 0) atomicAdd(&statsCur[0],  red[0] + red[1] + red[2] + red[3]);
    if (tid == 1) atomicAdd(&statsCur[16], red[4] + red[5] + red[6] + red[7]);
}

// ---------------- helpers ----------------------------------------------------
__global__ void finalizeStats(float* stats, const void* __restrict__ g,
                              const void* __restrict__ bt, float alpha, int cout,
                              float* mirror, const float* flagp)
{
    const bool isf = (*flagp > 0.5f);
    int c = threadIdx.x;
    if (c < cout) {
        const float invN = 1.f / (4.f * HW);
        float meanp = stats[c] * invN;
        float varp  = fmaxf(stats[16 + c] * invN - meanp * meanp, 0.f);
        float var_t = varp / (alpha * alpha);
        float sct = ldv(g, c, isf) * rsqrtf(var_t + 1e-5f);
        float scp = sct / alpha;
        float shp = ldv(bt, c, isf) - scp * meanp;
        stats[32 + c] = scp;
        stats[48 + c] = shp;
        if (mirror) { mirror[2 * c] = scp; mirror[2 * c + 1] = shp; mirror[32] = isf ? 1.f : 0.f; }
    }
}

__global__ void finalOut(const bf16* __restrict__ y6, const float* mirror,
                         void* __restrict__ out)
{
    float sc = mirror[0], sh = mirror[1];
    const bool isf = (mirror[32] > 0.5f);
    for (int idx = blockIdx.x * 256 + threadIdx.x; idx < 4 * HW; idx += gridDim.x * 256) {
        float v = fmaf(b2f(y6[idx]), sc, sh);
        if (isf) ((float*)out)[idx] = v;
        else     ((bf16*)out)[idx] = f2b(v);
    }
}

__global__ void zeroStats(float* stats)
{
    int i = blockIdx.x * 256 + threadIdx.x;
    if (i < 384) stats[i] = 0.f;
}

__global__ void fillOut(void* out, const float* flagp, float v)
{
    const bool isf = (*flagp > 0.5f);
    for (int idx = blockIdx.x * 256 + threadIdx.x; idx < 4 * HW; idx += gridDim.x * 256) {
        if (isf) ((float*)out)[idx] = v;
        else     ((bf16*)out)[idx] = f2b(v);
    }
}

// ---------------- launch ------------------------------------------------------
extern "C" void kernel_launch(void* const* d_in, const int* in_sizes, int n_in,
                              void* d_out, int out_size, void* d_ws, size_t ws_size,
                              hipStream_t stream)
{
    const void* x = d_in[0];
    #define W(L)  ((const void*)d_in[1 + ((L) - 1) * 4])
    #define B(L)  ((const void*)d_in[2 + ((L) - 1) * 4])
    #define G(L)  ((const void*)d_in[3 + ((L) - 1) * 4])
    #define BT(L) ((const void*)d_in[4 + ((L) - 1) * 4])

    float* stats = (float*)d_out;
    const float* flagp = stats + 380;
    float* wt1 = stats + 384;
    bf16* wb1 = (bf16*)wt1;                  // 3072 bf16 = 6144 B < 7744 B slot
    bf16* wb2 = (bf16*)(wt1 + 1936);         // 56*256 bf16
    bf16* wb3 = wb2 + 56 * 256;              // 30*256
    bf16* wb4 = wb3 + 30 * 256;              // 12*256
    bf16* wb5 = wb4 + 12 * 256;              // 12*256
    const size_t need = 2 * (size_t)64 * HW * sizeof(bf16);

    zeroStats<<<2, 256, 0, stream>>>(stats);
    probeKernel<<<1, 256, 0, stream>>>((const unsigned short*)x, stats);

    if (ws_size < need) {
        fillOut<<<2048, 256, 0, stream>>>(d_out, flagp, 3.0f);
        return;
    }

    transposeW1<<<12, 256, 0, stream>>>(W(1), wb1, flagp);
    transposeWB<<<56, 256, 0, stream>>>(W(2), wb2, 7, 8, flagp);
    transposeWB<<<30, 256, 0, stream>>>(W(3), wb3, 5, 6, flagp);
    transposeWB<<<12, 256, 0, stream>>>(W(4), wb4, 3, 4, flagp);
    transposeWB<<<12, 256, 0, stream>>>(W(5), wb5, 3, 4, flagp);

    bf16* bufA = (bf16*)d_ws;
    bf16* bufB = bufA + 64 * HW;
    float* mirror = (float*)bufA;

    dim3 grid(32, 32, 4), block(256);

    convFirstM<<<grid, block, 0, stream>>>(x, wb1, B(1), bufA, stats + 0, flagp);
    finalizeStats<<<1, 64, 0, stream>>>(stats + 0, G(1), BT(1), 121.f, 16, nullptr, flagp);

    conv16m<7, 11, 8><<<grid, block, 0, stream>>>(bufA, x, wb2, stats + 0, B(2), bufB, stats + 64, flagp);
    finalizeStats<<<1, 64, 0, stream>>>(stats + 64, G(2), BT(2), 49.f, 16, nullptr, flagp);

    conv16m<5, 17, 6><<<grid, block, 0, stream>>>(bufB, x, wb3, stats + 64, B(3), bufA, stats + 128, flagp);
    finalizeStats<<<1, 64, 0, stream>>>(stats + 128, G(3), BT(3), 25.f, 16, nullptr, flagp);

    conv16m<3, 21, 4><<<grid, block, 0, stream>>>(bufA, x, wb4, stats + 128, B(4), bufB, stats + 192, flagp);
    finalizeStats<<<1, 64, 0, stream>>>(stats + 192, G(4), BT(4), 9.f, 16, nullptr, flagp);

    conv16m<3, 23, 4><<<grid, block, 0, stream>>>(bufB, x, wb5, stats + 192, B(5), bufA, stats + 256, flagp);
    finalizeStats<<<1, 64, 0, stream>>>(stats + 256, G(5), BT(5), 9.f, 16, nullptr, flagp);

    bf16* y6 = (bf16*)bufB;
    layer6Kernel<<<grid, block, 0, stream>>>(bufA, x, stats + 256, W(6), B(6), y6, stats + 320, flagp);
    finalizeStats<<<1, 64, 0, stream>>>(stats + 320, G(6), BT(6), 1.f, 1, mirror, flagp);
    finalOut<<<2048, 256, 0, stream>>>(y6, mirror, d_out);

    #undef W
    #undef B
    #undef G
    #undef BT
}

// Round 8
// 792.187 us; speedup vs baseline: 1.1267x; 1.0143x over previous
//
#include <hip/hip_runtime.h>
#include <hip/hip_bf16.h>

// SparseConvNet on MI355X — Round 18: resident B-fragments (load after stage).
// R17 WIN: sliding-window A-reuse 213->193us, conflicts 2.78e7->8.9e6,
// MfmaUtil 26.5%. But VGPR_Count=96 proves Bf[28] (112 regs) is STILL
// rematerialized: ~450 VMEM B-loads + ~1300 VALU addr ops per wave in the
// hot loop (explains VALUBusy 33%, MfmaUtil cap). Root cause: Bf loads
// placed BEFORE the staging phase -> live range spans barrier+staging ->
// allocator remats regardless of budget (why R16's launch_bounds didn't
// help). Fix: move Bf load to AFTER the staging __syncthreads, directly
// before the MFMA loop; keep launch_bounds(256,2). wtB is 28KB -> L1-hot.
// Predict conv16m<7,11>: VGPR>=180, dur ~145us, MfmaUtil ~35%, total ~700us.

#define HW (1024 * 1024)
typedef __hip_bfloat16 bf16;
typedef __attribute__((ext_vector_type(8))) short s8v;     // 8 bf16 = 4 VGPR
typedef __attribute__((ext_vector_type(4))) float f4v;     // MFMA acc

__device__ __forceinline__ float b2f(bf16 v) { return __bfloat162float(v); }
__device__ __forceinline__ bf16  f2b(float v) { return __float2bfloat16(v); }
__device__ __forceinline__ short fbits(float v) {
    bf16 t = f2b(v); short s; __builtin_memcpy(&s, &t, 2); return s;
}
__device__ __forceinline__ float bs2f(short s) {
    bf16 t; __builtin_memcpy(&t, &s, 2); return __bfloat162float(t);
}

__device__ __forceinline__ float ldv(const void* p, int i, bool isf) {
    return isf ? ((const float*)p)[i] : b2f(((const bf16*)p)[i]);
}

__device__ __forceinline__ float wave_reduce(float v) {
    #pragma unroll
    for (int off = 32; off > 0; off >>= 1)
        v += __shfl_down(v, off, 64);
    return v;
}

// ---------------- dtype probe: 1.0 = fp32 dataset, 0.0 = bf16 ----------------
__global__ void probeKernel(const unsigned short* __restrict__ xb,
                            float* __restrict__ stats)
{
    __shared__ int sbad;
    const int tid = threadIdx.x;
    if (tid == 0) sbad = 0;
    __syncthreads();
    int bad = 0;
    for (int i = tid; i < 4096; i += 256) {
        unsigned u = ((unsigned)xb[i]) << 16;
        float v = __uint_as_float(u);
        if (!(v >= 0.f && v < 1.f)) bad = 1;
    }
    if (bad) sbad = 1;
    __syncthreads();
    if (tid == 0) stats[380] = sbad ? 1.f : 0.f;
}

// ---- L1 weights for MFMA B: wb[((k8*16+co)*8)+j] = w[co][tap(k8*8+j)], bf16 -
// tap axis: k = dy*16 + dx, K = 192; dy in 0..11, dx in 0..15; pad -> 0.
__global__ void transposeW1(const void* __restrict__ w, bf16* __restrict__ wb,
                            const float* flagp)
{
    const bool isf = (*flagp > 0.5f);
    int j = blockIdx.x * 256 + threadIdx.x;
    if (j < 3072) {
        int col8 = j & 7;
        int co = (j >> 3) & 15;
        int k8 = j >> 7;
        int k = k8 * 8 + col8;
        int dy = k >> 4, dx = k & 15;
        float v = (dy < 11 && dx < 11) ? ldv(w, co * 121 + dy * 11 + dx, isf) : 0.f;
        wb[j] = f2b(v);
    }
}

// ---- L2-5 weights, dx-padded layout: t = dy*DXP + dx (dx >= K -> 0) --------
// wtB[((t*16+co)*16)+c] = w[co][c][dy*K+dx]
__global__ void transposeWB(const void* __restrict__ w, bf16* __restrict__ wtB,
                            int K, int DXP, const float* flagp)
{
    const bool isf = (*flagp > 0.5f);
    int NT = K * DXP;
    int j = blockIdx.x * 256 + threadIdx.x;
    if (j < NT * 256) {
        int t = j >> 8, co = (j >> 4) & 15, c = j & 15;
        int dy = t / DXP, dx = t % DXP;
        float v = (dx < K) ? ldv(w, (co * 16 + c) * (K * K) + dy * K + dx, isf) : 0.f;
        wtB[j] = f2b(v);
    }
}

// ---------------- composed mask tile (separable max over WP window) ----------
template <int TM, int TK, int WP>
__device__ __forceinline__ void buildMaskTile(
    const void* __restrict__ mask0, bool isf, float* sm0, float* vm,
    float* mprev, int bx, int by, int tid)
{
    constexpr int H1 = (TM - 32) / 2;
    constexpr int H2 = (TK - 32) / 2;
    for (int i = tid; i < TM * TM; i += 256) {
        int yy = by - H1 + i / TM, xx = bx - H1 + i % TM;
        float m = 0.f;
        if ((unsigned)yy < 1024u && (unsigned)xx < 1024u)
            m = ldv(mask0, (yy << 10) + xx, isf);
        sm0[i] = m;
    }
    __syncthreads();
    for (int i = tid; i < TK * TM; i += 256) {
        int y = i / TM, xc = i % TM;
        float mx = 0.f;
        for (int d = 0; d < WP; ++d) mx = fmaxf(mx, sm0[(y + d) * TM + xc]);
        vm[i] = mx;
    }
    __syncthreads();
    for (int i = tid; i < TK * TK; i += 256) {
        int y = i / TK, xc = i % TK;
        int gy = by - H2 + y, gx = bx - H2 + xc;
        float mx = 0.f;
        if ((unsigned)gy < 1024u && (unsigned)gx < 1024u)
            for (int d = 0; d < WP; ++d) mx = fmaxf(mx, vm[y * TM + xc + d]);
        mprev[i] = mx;
    }
    __syncthreads();
}

__device__ __forceinline__ const void* maskChanPtr(const void* x, int n, bool isf) {
    return isf ? (const void*)((const float*)x + n * 2 * HW + HW)
               : (const void*)((const bf16*)x + n * 2 * HW + HW);
}

// ---------------- layer 1: cin=1, K=11 via MFMA implicit-GEMM ----------------
// Output NHWC: out[(n*HW + y*1024 + x)*16 + c], 32B-contiguous per quad.
__global__ __launch_bounds__(256) void convFirstM(
    const void* __restrict__ x, const bf16* __restrict__ wb1,
    const void* __restrict__ bias, bf16* __restrict__ out,
    float* statsCur, const float* flagp)
{
    constexpr int ST = 48, ROWS = 44, MT = 42;
    __shared__ alignas(16) short c0[ROWS * ST];
    __shared__ alignas(16) short c1[ROWS * ST + 2];
    __shared__ float smask[MT * MT];
    __shared__ float scs[32 * MT];
    __shared__ float sinv[1024];
    __shared__ float red[128];
    const bool isf = (*flagp > 0.5f);
    const int n = blockIdx.z;
    const int bx = blockIdx.x * 32, by = blockIdx.y * 32;
    const int tid = threadIdx.x, lane = tid & 63, wid = tid >> 6;
    const int nn = lane & 15, q = lane >> 4;

    // B fragments: lane = cout nn, k-block q; 6 K-steps of 32.
    s8v Bf[6];
    #pragma unroll
    for (int kb = 0; kb < 6; ++kb)
        Bf[kb] = *(const s8v*)(wb1 + ((kb * 4 + q) * 16 + nn) * 8);
    const float bv = ldv(bias, nn, isf);

    if (tid == 0) c1[0] = 0;

    // stage masked data (bf16, 2 shifted copies) + mask (fp32) tiles
    const int xoff = n * 2 * HW;
    for (int i = tid; i < ROWS * ST; i += 256) {
        int row = i / ST, col = i - row * ST;
        int yy = by - 5 + row, xx = bx - 5 + col;
        float d = 0.f, m = 0.f;
        if ((unsigned)yy < 1024u && (unsigned)xx < 1024u) {
            d = ldv(x, xoff + (yy << 10) + xx, isf);
            m = ldv(x, xoff + HW + (yy << 10) + xx, isf);
        }
        short b = fbits(d * m);
        c0[i] = b;
        c1[i + 1] = b;
        if (row < MT && col < MT) smask[row * MT + col] = m;
    }
    __syncthreads();

    // separable mask window sum: column pass
    for (int i = tid; i < 32 * MT; i += 256) {
        int r = i / MT, c = i - r * MT;
        float s = 0.f;
        #pragma unroll
        for (int dy = 0; dy < 11; ++dy) s += smask[(r + dy) * MT + c];
        scs[i] = s;
    }
    __syncthreads();
    // row pass -> per-pixel 121/(s+eps)
    for (int i = tid; i < 1024; i += 256) {
        int r = i >> 5, xc = i & 31;
        float s = 0.f;
        #pragma unroll
        for (int dx = 0; dx < 11; ++dx) s += scs[r * MT + xc + dx];
        sinv[i] = 121.f / (s + 1e-8f);
    }
    __syncthreads();

    // per-lane constant k-block decomposition: dy = kb*2 + dyq, dx0 = dxq
    const int dyq = q >> 1, dxq = (q & 1) << 3;
    const size_t nbase = (size_t)n * HW;
    float lsum = 0.f, lsq = 0.f;

    for (int mt = 0; mt < 16; ++mt) {
        int idx = wid * 16 + mt;
        int r = idx >> 1, g = idx & 1;
        int e = (r + dyq) * ST + (g << 4) + dxq + nn;   // elem idx, +96 per kb
        int s = e & 1;
        const unsigned* cp = s ? (const unsigned*)c1 : (const unsigned*)c0;
        int w = (e + s) >> 1;                            // word idx, +48 per kb
        f4v acc0 = {0.f, 0.f, 0.f, 0.f}, acc1 = {0.f, 0.f, 0.f, 0.f};
        #pragma unroll
        for (int kb = 0; kb < 6; ++kb) {
            union { unsigned u[4]; s8v v; } A;
            A.u[0] = cp[w];
            A.u[1] = cp[w + 1];
            A.u[2] = cp[w + 2];
            A.u[3] = cp[w + 3];
            if (kb & 1)
                acc1 = __builtin_amdgcn_mfma_f32_16x16x32_bf16(A.v, Bf[kb], acc1, 0, 0, 0);
            else
                acc0 = __builtin_amdgcn_mfma_f32_16x16x32_bf16(A.v, Bf[kb], acc0, 0, 0, 0);
            w += ST;
        }
        #pragma unroll
        for (int i2 = 0; i2 < 4; ++i2) {
            int px = (g << 4) + (q << 2) + i2;
            float y = fmaf(acc0[i2] + acc1[i2], sinv[(r << 5) + px], bv);
            out[((nbase + ((by + r) << 10) + bx + px) << 4) + nn] = f2b(y);
            lsum += y;
            lsq = fmaf(y, y, lsq);
        }
    }

    lsum += __shfl_xor(lsum, 16, 64);
    lsum += __shfl_xor(lsum, 32, 64);
    lsq  += __shfl_xor(lsq, 16, 64);
    lsq  += __shfl_xor(lsq, 32, 64);
    if (lane < 16) {
        red[wid * 32 + lane]      = lsum;
        red[wid * 32 + 16 + lane] = lsq;
    }
    __syncthreads();
    if (tid < 32) {
        float t = red[tid] + red[32 + tid] + red[64 + tid] + red[96 + tid];
        atomicAdd(&statsCur[tid], t);
    }
}

// ---------------- layers 2..5: MFMA implicit-GEMM, sliding-window A-reuse ----
// Wave owns 8 output rows x 32 cols. Iterate absolute row ar = 0..8+K-2:
// read each A-fragment ONCE per dx-pair j (2 halves), feed all valid dy via
// acc[ar-dy] (all loops unrolled -> static register indexing). dx padded to
// DXP with zero weights. Bf loaded AFTER the staging barrier so its live
// range is only the MFMA loop -> stays resident (launch_bounds(256,2)).
template <int K, int WP, int DXP>
__global__ __launch_bounds__(256, 2) void conv16m(
    const bf16* __restrict__ in, const void* __restrict__ x,
    const bf16* __restrict__ wtB, const float* statsPrev,
    const void* __restrict__ bias, bf16* __restrict__ out,
    float* statsCur, const float* flagp)
{
    constexpr int TK = 32 + K - 1;
    constexpr int TM = TK + WP - 1;
    constexpr int NJ = DXP / 2;            // dx-pairs per dy row
    constexpr int NK = K * NJ;             // B fragments
    constexpr int KK = K * K;
    constexpr int H2 = K / 2;
    __shared__ short sdatL[(TK * TK + 1) * 8];   // +1 pad s8v (zeroed)
    __shared__ short sdatH[(TK * TK + 1) * 8];
    __shared__ float mprev[TK * TK];
    __shared__ float sinv[1024];
    __shared__ float red[128];
    __shared__ float sss[32];
    const bool isf = (*flagp > 0.5f);
    const int n = blockIdx.z;
    const int bx = blockIdx.x * 32, by = blockIdx.y * 32;
    const int tid = threadIdx.x, lane = tid & 63, wid = tid >> 6;

    if (tid < 16) { sss[tid] = statsPrev[32 + tid]; sss[16 + tid] = statsPrev[48 + tid]; }

    buildMaskTile<TM, TK, WP>(maskChanPtr(x, n, isf), isf,
                              (float*)sdatL, (float*)sdatH, mprev, bx, by, tid);

    // separable sinv: col sums (into dead sdatH scratch) then row sums
    {
        float* cs = (float*)sdatH;          // 32*TK fp32 <= TK*TK*16 B
        for (int i = tid; i < 32 * TK; i += 256) {
            int r = i / TK, c = i - r * TK;
            float s = 0.f;
            #pragma unroll
            for (int dy = 0; dy < K; ++dy) s += mprev[(r + dy) * TK + c];
            cs[i] = s;
        }
        __syncthreads();
        for (int i = tid; i < 1024; i += 256) {
            int r = i >> 5, xc = i & 31;
            float s = 0.f;
            #pragma unroll
            for (int dx = 0; dx < K; ++dx) s += cs[r * TK + xc + dx];
            sinv[i] = (float)KK / (s + 1e-8f);
        }
        __syncthreads();
    }

    const int nn = lane & 15, quad = lane >> 4, c0 = (quad & 1) * 8, tl = quad >> 1;

    // stage: NHWC vector loads (2x16B per pixel), transform, split L/H halves
    {
        const bf16* inb = in + ((size_t)n * HW << 4);
        for (int p = tid; p < TK * TK; p += 256) {
            int yy = by - H2 + p / TK, xx = bx - H2 + p % TK;
            s8v lo = {0,0,0,0,0,0,0,0}, hi = {0,0,0,0,0,0,0,0};
            if ((unsigned)yy < 1024u && (unsigned)xx < 1024u) {
                float mv = mprev[p];
                const s8v* q = (const s8v*)(inb + ((size_t)((yy << 10) + xx) << 4));
                s8v rl = q[0], rh = q[1];
                #pragma unroll
                for (int c = 0; c < 8; ++c) {
                    float yv = bs2f(rl[c]);
                    lo[c] = fbits(fmaxf(fmaf(sss[c], yv, sss[16 + c]), 0.f) * mv);
                }
                #pragma unroll
                for (int c = 0; c < 8; ++c) {
                    float yv = bs2f(rh[c]);
                    hi[c] = fbits(fmaxf(fmaf(sss[c + 8], yv, sss[24 + c]), 0.f) * mv);
                }
            }
            ((s8v*)sdatL)[p] = lo;
            ((s8v*)sdatH)[p] = hi;
        }
        if (tid == 0) {                      // zero the pad slot (index TK*TK)
            s8v z = {0,0,0,0,0,0,0,0};
            ((s8v*)sdatL)[TK * TK] = z;
            ((s8v*)sdatH)[TK * TK] = z;
        }
    }
    __syncthreads();

    // B fragments: loaded here (post-barrier) so live range = MFMA loop only.
    s8v Bf[NK];
    #pragma unroll
    for (int kk = 0; kk < NK; ++kk) {
        int dy = kk / NJ, jj = kk % NJ;
        int t = dy * DXP + 2 * jj + tl;
        Bf[kk] = *(const s8v*)(wtB + ((t * 16 + nn) * 16 + c0));
    }

    const float bv = ldv(bias, nn, isf);
    const s8v* Abase = (const s8v*)((quad & 1) ? sdatH : sdatL);
    const size_t nbase = (size_t)n * HW;
    const int r0 = wid * 8;

    f4v acc[8][2];
    #pragma unroll
    for (int rr = 0; rr < 8; ++rr) {
        acc[rr][0] = f4v{0.f, 0.f, 0.f, 0.f};
        acc[rr][1] = f4v{0.f, 0.f, 0.f, 0.f};
    }

    #pragma unroll
    for (int ar = 0; ar < 8 + K - 1; ++ar) {
        #pragma unroll
        for (int j = 0; j < NJ; ++j) {
            const int base = (r0 + ar) * TK + nn + 2 * j + tl;
            const s8v F0 = Abase[base];
            const s8v F1 = Abase[base + 16];
            #pragma unroll
            for (int dy = 0; dy < K; ++dy) {
                if (ar - dy >= 0 && ar - dy < 8) {
                    acc[ar - dy][0] = __builtin_amdgcn_mfma_f32_16x16x32_bf16(
                        F0, Bf[dy * NJ + j], acc[ar - dy][0], 0, 0, 0);
                    acc[ar - dy][1] = __builtin_amdgcn_mfma_f32_16x16x32_bf16(
                        F1, Bf[dy * NJ + j], acc[ar - dy][1], 0, 0, 0);
                }
            }
        }
    }

    float lsum = 0.f, lsq = 0.f;
    #pragma unroll
    for (int rr = 0; rr < 8; ++rr) {
        const int r = r0 + rr;
        #pragma unroll
        for (int h = 0; h < 2; ++h) {
            const int xh = h << 4;
            #pragma unroll
            for (int i = 0; i < 4; ++i) {
                int m = quad * 4 + i;
                float y = fmaf(acc[rr][h][i], sinv[r * 32 + xh + m], bv);
                out[((nbase + ((by + r) << 10) + bx + xh + m) << 4) + nn] = f2b(y);
                lsum += y;
                lsq = fmaf(y, y, lsq);
            }
        }
    }

    lsum += __shfl_xor(lsum, 16, 64);
    lsum += __shfl_xor(lsum, 32, 64);
    lsq  += __shfl_xor(lsq, 16, 64);
    lsq  += __shfl_xor(lsq, 32, 64);
    if (lane < 16) {
        red[wid * 32 + lane]      = lsum;
        red[wid * 32 + 16 + lane] = lsq;
    }
    __syncthreads();
    if (tid < 32) {
        float t = red[tid] + red[32 + tid] + red[64 + tid] + red[96 + tid];
        atomicAdd(&statsCur[tid], t);
    }
}

// ---------------- layer 6: 1x1 conv to 1 channel (NHWC input) ----------------
__global__ __launch_bounds__(256) void layer6Kernel(
    const bf16* __restrict__ in, const void* __restrict__ x,
    const float* statsPrev, const void* __restrict__ w6,
    const void* __restrict__ b6, bf16* __restrict__ y6,
    float* statsCur, const float* flagp)
{
    constexpr int WP = 25, TM = 56, TK = 32;
    __shared__ float sm0[TM * TM];
    __shared__ float vm[TK * TM];
    __shared__ float m5[TK * TK];
    __shared__ float red[8];
    __shared__ float ssc[16], ssh[16];
    const bool isf = (*flagp > 0.5f);
    const int n = blockIdx.z;
    const int bx = blockIdx.x * 32, by = blockIdx.y * 32;
    const int tid = threadIdx.x;
    const int tx = tid & 31, ty0 = (tid >> 5) << 2;

    if (tid < 16) {
        ssc[tid] = statsPrev[32 + tid];
        ssh[tid] = statsPrev[48 + tid];
    }

    buildMaskTile<TM, TK, WP>(maskChanPtr(x, n, isf), isf, sm0, vm, m5, bx, by, tid);

    float wv[16];
    #pragma unroll
    for (int c = 0; c < 16; ++c) wv[c] = ldv(w6, c, isf);
    const float bias = ldv(b6, 0, isf);

    float lsum = 0.f, lsq = 0.f;
    #pragma unroll
    for (int p = 0; p < 4; ++p) {
        int yy = by + ty0 + p, xx = bx + tx;
        float m = m5[(ty0 + p) * TK + tx];
        const s8v* q = (const s8v*)(in + (((size_t)n * HW + (yy << 10) + xx) << 4));
        s8v rl = q[0], rh = q[1];
        float a = 0.f;
        #pragma unroll
        for (int c = 0; c < 8; ++c) {
            float h = fmaxf(fmaf(ssc[c], bs2f(rl[c]), ssh[c]), 0.f);
            a = fmaf(h, wv[c], a);
        }
        #pragma unroll
        for (int c = 0; c < 8; ++c) {
            float h = fmaxf(fmaf(ssc[c + 8], bs2f(rh[c]), ssh[c + 8]), 0.f);
            a = fmaf(h, wv[c + 8], a);
        }
        float yv = a * m / (m + 1e-8f) + bias;
        y6[n * HW + (yy << 10) + xx] = f2b(yv);
        lsum += yv;
        lsq = fmaf(yv, yv, lsq);
    }
    lsum = wave_reduce(lsum);
    lsq = wave_reduce(lsq);
    const int wid = tid >> 6, lane = tid & 63;
    if (lane == 0) { red[wid] = lsum; red[4 + wid] = lsq; }
    __syncthreads();
    if (tid == 0) atomicAdd(&statsCur[0],  red[0] + red[1] + red[2] + red[3]);
    if (tid == 1) atomicAdd(&statsCur[16], red[4] + red[5] + red[6] + red[7]);
}

// ---------------- helpers ----------------------------------------------------
__global__ void finalizeStats(float* stats, const void* __restrict__ g,
                              const void* __restrict__ bt, float alpha, int cout,
                              float* mirror, const float* flagp)
{
    const bool isf = (*flagp > 0.5f);
    int c = threadIdx.x;
    if (c < cout) {
        const float invN = 1.f / (4.f * HW);
        float meanp = stats[c] * invN;
        float varp  = fmaxf(stats[16 + c] * invN - meanp * meanp, 0.f);
        float var_t = varp / (alpha * alpha);
        float sct = ldv(g, c, isf) * rsqrtf(var_t + 1e-5f);
        float scp = sct / alpha;
        float shp = ldv(bt, c, isf) - scp * meanp;
        stats[32 + c] = scp;
        stats[48 + c] = shp;
        if (mirror) { mirror[2 * c] = scp; mirror[2 * c + 1] = shp; mirror[32] = isf ? 1.f : 0.f; }
    }
}

__global__ void finalOut(const bf16* __restrict__ y6, const float* mirror,
                         void* __restrict__ out)
{
    float sc = mirror[0], sh = mirror[1];
    const bool isf = (mirror[32] > 0.5f);
    for (int idx = blockIdx.x * 256 + threadIdx.x; idx < 4 * HW; idx += gridDim.x * 256) {
        float v = fmaf(b2f(y6[idx]), sc, sh);
        if (isf) ((float*)out)[idx] = v;
        else     ((bf16*)out)[idx] = f2b(v);
    }
}

__global__ void zeroStats(float* stats)
{
    int i = blockIdx.x * 256 + threadIdx.x;
    if (i < 384) stats[i] = 0.f;
}

__global__ void fillOut(void* out, const float* flagp, float v)
{
    const bool isf = (*flagp > 0.5f);
    for (int idx = blockIdx.x * 256 + threadIdx.x; idx < 4 * HW; idx += gridDim.x * 256) {
        if (isf) ((float*)out)[idx] = v;
        else     ((bf16*)out)[idx] = f2b(v);
    }
}

// ---------------- launch ------------------------------------------------------
extern "C" void kernel_launch(void* const* d_in, const int* in_sizes, int n_in,
                              void* d_out, int out_size, void* d_ws, size_t ws_size,
                              hipStream_t stream)
{
    const void* x = d_in[0];
    #define W(L)  ((const void*)d_in[1 + ((L) - 1) * 4])
    #define B(L)  ((const void*)d_in[2 + ((L) - 1) * 4])
    #define G(L)  ((const void*)d_in[3 + ((L) - 1) * 4])
    #define BT(L) ((const void*)d_in[4 + ((L) - 1) * 4])

    float* stats = (float*)d_out;
    const float* flagp = stats + 380;
    float* wt1 = stats + 384;
    bf16* wb1 = (bf16*)wt1;                  // 3072 bf16 = 6144 B < 7744 B slot
    bf16* wb2 = (bf16*)(wt1 + 1936);         // 56*256 bf16
    bf16* wb3 = wb2 + 56 * 256;              // 30*256
    bf16* wb4 = wb3 + 30 * 256;              // 12*256
    bf16* wb5 = wb4 + 12 * 256;              // 12*256
    const size_t need = 2 * (size_t)64 * HW * sizeof(bf16);

    zeroStats<<<2, 256, 0, stream>>>(stats);
    probeKernel<<<1, 256, 0, stream>>>((const unsigned short*)x, stats);

    if (ws_size < need) {
        fillOut<<<2048, 256, 0, stream>>>(d_out, flagp, 3.0f);
        return;
    }

    transposeW1<<<12, 256, 0, stream>>>(W(1), wb1, flagp);
    transposeWB<<<56, 256, 0, stream>>>(W(2), wb2, 7, 8, flagp);
    transposeWB<<<30, 256, 0, stream>>>(W(3), wb3, 5, 6, flagp);
    transposeWB<<<12, 256, 0, stream>>>(W(4), wb4, 3, 4, flagp);
    transposeWB<<<12, 256, 0, stream>>>(W(5), wb5, 3, 4, flagp);

    bf16* bufA = (bf16*)d_ws;
    bf16* bufB = bufA + 64 * HW;
    float* mirror = (float*)bufA;

    dim3 grid(32, 32, 4), block(256);

    convFirstM<<<grid, block, 0, stream>>>(x, wb1, B(1), bufA, stats + 0, flagp);
    finalizeStats<<<1, 64, 0, stream>>>(stats + 0, G(1), BT(1), 121.f, 16, nullptr, flagp);

    conv16m<7, 11, 8><<<grid, block, 0, stream>>>(bufA, x, wb2, stats + 0, B(2), bufB, stats + 64, flagp);
    finalizeStats<<<1, 64, 0, stream>>>(stats + 64, G(2), BT(2), 49.f, 16, nullptr, flagp);

    conv16m<5, 17, 6><<<grid, block, 0, stream>>>(bufB, x, wb3, stats + 64, B(3), bufA, stats + 128, flagp);
    finalizeStats<<<1, 64, 0, stream>>>(stats + 128, G(3), BT(3), 25.f, 16, nullptr, flagp);

    conv16m<3, 21, 4><<<grid, block, 0, stream>>>(bufA, x, wb4, stats + 128, B(4), bufB, stats + 192, flagp);
    finalizeStats<<<1, 64, 0, stream>>>(stats + 192, G(4), BT(4), 9.f, 16, nullptr, flagp);

    conv16m<3, 23, 4><<<grid, block, 0, stream>>>(bufB, x, wb5, stats + 192, B(5), bufA, stats + 256, flagp);
    finalizeStats<<<1, 64, 0, stream>>>(stats + 256, G(5), BT(5), 9.f, 16, nullptr, flagp);

    bf16* y6 = (bf16*)bufB;
    layer6Kernel<<<grid, block, 0, stream>>>(bufA, x, stats + 256, W(6), B(6), y6, stats + 320, flagp);
    finalizeStats<<<1, 64, 0, stream>>>(stats + 320, G(6), BT(6), 1.f, 1, mirror, flagp);
    finalOut<<<2048, 256, 0, stream>>>(y6, mirror, d_out);

    #undef W
    #undef B
    #undef G
    #undef BT
}